// Round 2
// baseline (2743.956 us; speedup 1.0000x reference)
//
#include <hip/hip_runtime.h>
#include <hip/hip_bf16.h>

// ---------------- problem constants ----------------
#define B_    128
#define NN    2000
#define C_    256
#define E_    64000
#define CIN   64
#define ROWST 2064   // CIN + NN
#define CEMB  128
#define HAZ1  512
#define HAZ2  256
#define FUSD  640    // CEMB + 2*C_

// ---------------- workspace layout (bytes) ----------------
// misc block first (fixed), then two chunk-sized x buffers.
static constexpr size_t OFF_DEGO = 0;        // int[2000]
static constexpr size_t OFF_DEGI = 8000;     // int[2000]
static constexpr size_t OFF_CUR  = 16000;    // int[2000]
static constexpr size_t OFF_WOUT = 24000;    // float[2000]
static constexpr size_t OFF_WIN  = 32000;    // float[2000]
static constexpr size_t OFF_IOFF = 40000;    // int[2001] (padded)
static constexpr size_t OFF_CSRC = 48192;    // int[64000]
static constexpr size_t OFF_CSRW = 304192;   // float[64000]
static constexpr size_t OFF_HG   = 560192;   // float[128*512]
static constexpr size_t OFF_EMB  = 822336;   // float[128*128]
static constexpr size_t OFF_H1   = 887872;   // float[128*512]
static constexpr size_t OFF_H2   = 1150016;  // float[128*256]
static constexpr size_t OFF_PSUM = 1281088;  // float[128*8*256]
static constexpr size_t OFF_PMAX = 2329664;  // float[128*8*256] (ends 3378240)
static constexpr size_t OFF_XA   = 4194304;  // chunk buffer A
static constexpr size_t SZ_B1    = (size_t)NN * C_ * sizeof(float); // 2,048,000 per batch elem

// ---------------- utility ----------------
__global__ void k_zero(float* p, int n) {
    int i = blockIdx.x * 256 + threadIdx.x;
    if (i < n) p[i] = 0.f;
}

__global__ void k_deg(const int* __restrict__ src, const int* __restrict__ dst,
                      int* __restrict__ dego, int* __restrict__ degi) {
    int e = blockIdx.x * 256 + threadIdx.x;
    if (e < E_) {
        atomicAdd(&dego[src[e]], 1);
        atomicAdd(&degi[dst[e]], 1);
    }
}

__global__ void k_norm(const int* __restrict__ dego, const int* __restrict__ degi,
                       float* __restrict__ wout, float* __restrict__ win) {
    int n = blockIdx.x * 256 + threadIdx.x;
    if (n < NN) {
        wout[n] = rsqrtf(fmaxf((float)dego[n], 1.f));
        win[n]  = rsqrtf(fmaxf((float)degi[n], 1.f));
    }
}

// exclusive scan of in-degrees -> in_off[0..NN], one block of 512 threads
__global__ void k_scan(const int* __restrict__ degi, int* __restrict__ ioff) {
    __shared__ int part[512];
    int t = threadIdx.x;
    int base = t * 4;
    int v[4]; int s = 0;
#pragma unroll
    for (int i = 0; i < 4; i++) {
        int idx = base + i;
        v[i] = (idx < NN) ? degi[idx] : 0;
        s += v[i];
    }
    part[t] = s;
    __syncthreads();
    for (int o = 1; o < 512; o <<= 1) {
        int x = 0;
        if (t >= o) x = part[t - o];
        __syncthreads();
        part[t] += x;
        __syncthreads();
    }
    int run = (t == 0) ? 0 : part[t - 1];
#pragma unroll
    for (int i = 0; i < 4; i++) {
        int idx = base + i;
        if (idx <= NN) ioff[idx] = run;
        run += v[i];
    }
}

__global__ void k_fill(const int* __restrict__ src, const int* __restrict__ dst,
                       const float* __restrict__ wout, const float* __restrict__ win,
                       const int* __restrict__ ioff, int* __restrict__ cursor,
                       int* __restrict__ csrc, float* __restrict__ csrw) {
    int e = blockIdx.x * 256 + threadIdx.x;
    if (e < E_) {
        int d = dst[e];
        int s = src[e];
        int p = atomicAdd(&cursor[d], 1);
        int i = ioff[d] + p;
        csrc[i] = s;
        csrw[i] = wout[s] * win[d];
    }
}

// layer 0: agg over scalar node feature, expand through W0 (1x256) + b0, relu
__global__ __launch_bounds__(64) void k_layer0(
        const float* __restrict__ inp, const int* __restrict__ ioff,
        const int* __restrict__ csrc, const float* __restrict__ csrw,
        const float* __restrict__ W0, const float* __restrict__ b0,
        float* __restrict__ xout, int b0g) {
    int n = blockIdx.x, bl = blockIdx.y, t = threadIdx.x;
    int e0 = ioff[n], e1 = ioff[n + 1];
    const float* row = inp + (size_t)(b0g + bl) * ROWST + CIN;
    float a = 0.f;
    for (int i = e0; i < e1; i++) a += csrw[i] * row[csrc[i]];
    float4 w  = *reinterpret_cast<const float4*>(&W0[t * 4]);
    float4 bb = *reinterpret_cast<const float4*>(&b0[t * 4]);
    float4 o;
    o.x = fmaxf(a * w.x + bb.x, 0.f);
    o.y = fmaxf(a * w.y + bb.y, 0.f);
    o.z = fmaxf(a * w.z + bb.z, 0.f);
    o.w = fmaxf(a * w.w + bb.w, 0.f);
    *reinterpret_cast<float4*>(&xout[((size_t)bl * NN + n) * C_ + t * 4]) = o;
}

// layers 1,2 aggregation: xout[b,n,:] = sum_e w_e * xin[b,src_e,:]  (chunk-local b)
__global__ __launch_bounds__(64) void k_agg(
        const float* __restrict__ xin, const int* __restrict__ ioff,
        const int* __restrict__ csrc, const float* __restrict__ csrw,
        float* __restrict__ xout) {
    int n = blockIdx.x, bl = blockIdx.y, t = threadIdx.x;
    int e0 = ioff[n], e1 = ioff[n + 1];
    const float* xb = xin + (size_t)bl * NN * C_;
    float4 acc = {0.f, 0.f, 0.f, 0.f};
    for (int i = e0; i < e1; i++) {
        int s   = csrc[i];
        float w = csrw[i];
        float4 v = *reinterpret_cast<const float4*>(&xb[(size_t)s * C_ + t * 4]);
        acc.x += w * v.x; acc.y += w * v.y; acc.z += w * v.z; acc.w += w * v.w;
    }
    *reinterpret_cast<float4*>(&xout[((size_t)bl * NN + n) * C_ + t * 4]) = acc;
}

// C = relu(A @ W + bias), A: (M,256) row-major, W: (256,256) row-major
#define BM 64
#define BN 64
#define BK 16
__global__ __launch_bounds__(256) void k_gemm(
        const float* __restrict__ A, const float* __restrict__ W,
        const float* __restrict__ bias, float* __restrict__ Cout) {
    __shared__ float As[BK][BM + 4];  // transposed A tile
    __shared__ float Bs[BK][BN + 4];
    int tid = threadIdx.x;
    int tx = tid & 15, ty = tid >> 4;
    int m0 = blockIdx.x * BM;
    int n0 = blockIdx.y * BN;
    float acc[4][4] = {};
    for (int k0 = 0; k0 < 256; k0 += BK) {
        {   // A tile: 64 rows x 16 k, float4 per thread
            int r = tid >> 2;
            int c = (tid & 3) * 4;
            float4 av = *reinterpret_cast<const float4*>(&A[(size_t)(m0 + r) * 256 + k0 + c]);
            As[c + 0][r] = av.x; As[c + 1][r] = av.y;
            As[c + 2][r] = av.z; As[c + 3][r] = av.w;
        }
        {   // B tile: 16 k x 64 cols
            int r = tid >> 4;
            int c = (tid & 15) * 4;
            float4 bv = *reinterpret_cast<const float4*>(&W[(size_t)(k0 + r) * 256 + n0 + c]);
            *reinterpret_cast<float4*>(&Bs[r][c]) = bv;
        }
        __syncthreads();
#pragma unroll
        for (int kk = 0; kk < BK; kk++) {
            float4 a4 = *reinterpret_cast<const float4*>(&As[kk][ty * 4]);
            float4 b4 = *reinterpret_cast<const float4*>(&Bs[kk][tx * 4]);
            float a[4] = {a4.x, a4.y, a4.z, a4.w};
            float b[4] = {b4.x, b4.y, b4.z, b4.w};
#pragma unroll
            for (int i = 0; i < 4; i++)
#pragma unroll
                for (int j = 0; j < 4; j++) acc[i][j] += a[i] * b[j];
        }
        __syncthreads();
    }
#pragma unroll
    for (int i = 0; i < 4; i++) {
        size_t m = m0 + ty * 4 + i;
#pragma unroll
        for (int j = 0; j < 4; j++) {
            int n = n0 + tx * 4 + j;
            Cout[m * 256 + n] = fmaxf(acc[i][j] + bias[n], 0.f);
        }
    }
}

// pooling partials: 8 splits of 250 rows  (chunk-local b)
__global__ __launch_bounds__(256) void k_pool(
        const float* __restrict__ x, float* __restrict__ psum, float* __restrict__ pmax) {
    int bl = blockIdx.x, s = blockIdx.y, c = threadIdx.x;
    const float* xb = x + (size_t)bl * NN * C_;
    int n0 = s * 250;
    float sum = 0.f, mx = -INFINITY;
    for (int i = 0; i < 250; i++) {
        float v = xb[(size_t)(n0 + i) * C_ + c];
        sum += v;
        mx = fmaxf(mx, v);
    }
    psum[((size_t)bl * 8 + s) * C_ + c] = sum;
    pmax[((size_t)bl * 8 + s) * C_ + c] = mx;
}

__global__ __launch_bounds__(256) void k_pool_combine(
        const float* __restrict__ psum, const float* __restrict__ pmax,
        float* __restrict__ hg, int b0g) {
    int bl = blockIdx.x, c = threadIdx.x;
    float s = 0.f, m = -INFINITY;
#pragma unroll
    for (int i = 0; i < 8; i++) {
        s += psum[((size_t)bl * 8 + i) * C_ + c];
        m = fmaxf(m, pmax[((size_t)bl * 8 + i) * C_ + c]);
    }
    size_t b = b0g + bl;
    hg[b * 512 + c]       += fmaxf(s * (1.f / (float)NN), 0.f);
    hg[b * 512 + 256 + c] += fmaxf(m, 0.f);
}

__global__ __launch_bounds__(128) void k_embed(
        const float* __restrict__ inp, const float* __restrict__ We,
        float* __restrict__ emb) {
    int b = blockIdx.x, c = threadIdx.x;
    const float* row = inp + (size_t)b * ROWST;
    float a = 0.f;
    for (int k = 0; k < CIN; k++) a += row[k] * We[k * CEMB + c];
    emb[b * CEMB + c] = fmaxf(a, 0.f);
}

__global__ __launch_bounds__(512) void k_mlp1(
        const float* __restrict__ emb, const float* __restrict__ hg,
        const float* __restrict__ Wh1, const float* __restrict__ bh1,
        float* __restrict__ h1) {
    __shared__ float fus[FUSD];
    int b = blockIdx.x, j = threadIdx.x;
    if (j < CEMB) fus[j] = emb[b * CEMB + j];
    fus[CEMB + j] = hg[(size_t)b * 512 + j];
    __syncthreads();
    float a = bh1[j];
    for (int k = 0; k < FUSD; k++) a += fus[k] * Wh1[(size_t)k * HAZ1 + j];
    h1[(size_t)b * HAZ1 + j] = fmaxf(a, 0.f);
}

__global__ __launch_bounds__(256) void k_mlp2(
        const float* __restrict__ h1, const float* __restrict__ Wh2,
        const float* __restrict__ bh2, float* __restrict__ h2) {
    __shared__ float f2[HAZ1];
    int b = blockIdx.x, j = threadIdx.x;
    f2[j]       = h1[(size_t)b * HAZ1 + j];
    f2[256 + j] = h1[(size_t)b * HAZ1 + 256 + j];
    __syncthreads();
    float a = bh2[j];
    for (int k = 0; k < HAZ1; k++) a += f2[k] * Wh2[(size_t)k * HAZ2 + j];
    h2[(size_t)b * HAZ2 + j] = fmaxf(a, 0.f);
}

__global__ __launch_bounds__(256) void k_out(
        const float* __restrict__ h2, const float* __restrict__ Wh3,
        float* __restrict__ out) {
    __shared__ float red[256];
    int b = blockIdx.x, t = threadIdx.x;
    red[t] = h2[(size_t)b * HAZ2 + t] * Wh3[t];
    __syncthreads();
    for (int o = 128; o > 0; o >>= 1) {
        if (t < o) red[t] += red[t + o];
        __syncthreads();
    }
    if (t == 0) out[b] = red[0];
}

// ---------------- launch ----------------
extern "C" void kernel_launch(void* const* d_in, const int* in_sizes, int n_in,
                              void* d_out, int out_size, void* d_ws, size_t ws_size,
                              hipStream_t stream) {
    const float* inp = (const float*)d_in[0];
    const int*   src = (const int*)d_in[1];
    const int*   dst = (const int*)d_in[2];
    const float* W0  = (const float*)d_in[3];
    const float* b0  = (const float*)d_in[4];
    const float* W1  = (const float*)d_in[5];
    const float* b1  = (const float*)d_in[6];
    const float* W2  = (const float*)d_in[7];
    const float* b2  = (const float*)d_in[8];
    const float* We  = (const float*)d_in[9];
    const float* Wh1 = (const float*)d_in[10];
    const float* bh1 = (const float*)d_in[11];
    const float* Wh2 = (const float*)d_in[12];
    const float* bh2 = (const float*)d_in[13];
    const float* Wh3 = (const float*)d_in[14];
    float* out = (float*)d_out;

    char* ws = (char*)d_ws;
    int*   dego = (int*)(ws + OFF_DEGO);
    int*   degi = (int*)(ws + OFF_DEGI);
    int*   cur  = (int*)(ws + OFF_CUR);
    float* wout = (float*)(ws + OFF_WOUT);
    float* win  = (float*)(ws + OFF_WIN);
    int*   ioff = (int*)(ws + OFF_IOFF);
    int*   csrc = (int*)(ws + OFF_CSRC);
    float* csrw = (float*)(ws + OFF_CSRW);
    float* hg   = (float*)(ws + OFF_HG);
    float* emb  = (float*)(ws + OFF_EMB);
    float* h1   = (float*)(ws + OFF_H1);
    float* h2   = (float*)(ws + OFF_H2);
    float* psum = (float*)(ws + OFF_PSUM);
    float* pmax = (float*)(ws + OFF_PMAX);

    // ---- choose batch-chunk size CB so the footprint fits ws_size ----
    // need = OFF_XA + 2 * CB * SZ_B1.  CB in {128,64,32,16,8,4}
    // (CB multiple of 4 keeps CB*2000 divisible by BM=64).
    int CB = 128;
    while (CB > 4 && OFF_XA + 2ull * (size_t)CB * SZ_B1 > ws_size) CB >>= 1;
    int nchunk = B_ / CB;

    float* xA = (float*)(ws + OFF_XA);
    float* xB = (float*)(ws + OFF_XA + (size_t)CB * SZ_B1);

    // zero: deg_out/deg_in/cursor (6000 ints) and hg (65536 floats)
    k_zero<<<dim3((6000 + 255) / 256), 256, 0, stream>>>((float*)dego, 6000);
    k_zero<<<dim3((65536 + 255) / 256), 256, 0, stream>>>(hg, 65536);

    // graph normalization + CSR build
    k_deg<<<dim3((E_ + 255) / 256), 256, 0, stream>>>(src, dst, dego, degi);
    k_norm<<<dim3((NN + 255) / 256), 256, 0, stream>>>(dego, degi, wout, win);
    k_scan<<<1, 512, 0, stream>>>(degi, ioff);
    k_fill<<<dim3((E_ + 255) / 256), 256, 0, stream>>>(src, dst, wout, win, ioff, cur, csrc, csrw);

    dim3 gridNB(NN, CB);
    dim3 gridGemm((CB * NN) / BM, C_ / BN);
    dim3 gridPool(CB, 8);

    for (int c = 0; c < nchunk; ++c) {
        int b0g = c * CB;

        // layer 0: agg (C=1) + expand -> xA
        k_layer0<<<gridNB, 64, 0, stream>>>(inp, ioff, csrc, csrw, W0, b0, xA, b0g);
        k_pool<<<gridPool, 256, 0, stream>>>(xA, psum, pmax);
        k_pool_combine<<<CB, 256, 0, stream>>>(psum, pmax, hg, b0g);

        // layer 1: agg xA -> xB, gemm xB @ W1 -> xA
        k_agg<<<gridNB, 64, 0, stream>>>(xA, ioff, csrc, csrw, xB);
        k_gemm<<<gridGemm, 256, 0, stream>>>(xB, W1, b1, xA);
        k_pool<<<gridPool, 256, 0, stream>>>(xA, psum, pmax);
        k_pool_combine<<<CB, 256, 0, stream>>>(psum, pmax, hg, b0g);

        // layer 2: agg xA -> xB, gemm xB @ W2 -> xA
        k_agg<<<gridNB, 64, 0, stream>>>(xA, ioff, csrc, csrw, xB);
        k_gemm<<<gridGemm, 256, 0, stream>>>(xB, W2, b2, xA);
        k_pool<<<gridPool, 256, 0, stream>>>(xA, psum, pmax);
        k_pool_combine<<<CB, 256, 0, stream>>>(psum, pmax, hg, b0g);
    }

    // head
    k_embed<<<B_, 128, 0, stream>>>(inp, We, emb);
    k_mlp1<<<B_, 512, 0, stream>>>(emb, hg, Wh1, bh1, h1);
    k_mlp2<<<B_, 256, 0, stream>>>(h1, Wh2, bh2, h2);
    k_out<<<B_, 256, 0, stream>>>(h2, Wh3, out);
}

// Round 3
// 1549.044 us; speedup vs baseline: 1.7714x; 1.7714x over previous
//
#include <hip/hip_runtime.h>
#include <hip/hip_bf16.h>

// ---------------- problem constants ----------------
#define B_    128
#define NN    2000
#define C_    256
#define E_    64000
#define CIN   64
#define ROWST 2064   // CIN + NN
#define CEMB  128
#define HAZ1  512
#define HAZ2  256
#define FUSD  640    // CEMB + 2*C_

typedef unsigned short u16;
typedef __attribute__((ext_vector_type(8))) short short8;
typedef __attribute__((ext_vector_type(4))) float f32x4;

// ---------------- workspace layout (bytes) ----------------
static constexpr size_t OFF_DEGO = 0;        // int[2000]
static constexpr size_t OFF_DEGI = 8000;     // int[2000]
static constexpr size_t OFF_CUR  = 16000;    // int[2000]
static constexpr size_t OFF_WOUT = 24000;    // float[2000]
static constexpr size_t OFF_WIN  = 32000;    // float[2000]
static constexpr size_t OFF_IOFF = 40000;    // int[2001] (padded)
static constexpr size_t OFF_CSRC = 48192;    // int[64000]
static constexpr size_t OFF_CSRW = 304192;   // float[64000]
static constexpr size_t OFF_HG   = 560192;   // float[128*512]
static constexpr size_t OFF_EMB  = 822336;   // float[128*128]
static constexpr size_t OFF_H1   = 887872;   // float[128*512]
static constexpr size_t OFF_H2   = 1150016;  // float[128*256]
static constexpr size_t OFF_PSUM = 1281088;  // float[128*8*256]
static constexpr size_t OFF_PMAX = 2329664;  // float[128*8*256] (ends 3378240)
static constexpr size_t OFF_WT1H = 3407872;  // u16[256*256] = 131072 B
static constexpr size_t OFF_WT1L = 3538944;
static constexpr size_t OFF_WT2H = 3670016;
static constexpr size_t OFF_WT2L = 3801088;  // ends 3932160
static constexpr size_t OFF_XA   = 4194304;  // chunk buffer A
static constexpr size_t SZ_B1    = (size_t)NN * C_ * sizeof(float); // 2,048,000 per batch elem

// ---------------- bf16 helpers (RNE) ----------------
__device__ __forceinline__ u16 f2bf(float f) {
    union { float f; unsigned u; } v; v.f = f;
    unsigned u = v.u;
    unsigned r = (u + 0x7FFFu + ((u >> 16) & 1u)) >> 16;
    return (u16)r;
}
__device__ __forceinline__ float bf2f(u16 h) {
    union { unsigned u; float f; } v; v.u = ((unsigned)h) << 16;
    return v.f;
}

// ---------------- utility ----------------
__global__ void k_zero(float* p, int n) {
    int i = blockIdx.x * 256 + threadIdx.x;
    if (i < n) p[i] = 0.f;
}

__global__ void k_deg(const int* __restrict__ src, const int* __restrict__ dst,
                      int* __restrict__ dego, int* __restrict__ degi) {
    int e = blockIdx.x * 256 + threadIdx.x;
    if (e < E_) {
        atomicAdd(&dego[src[e]], 1);
        atomicAdd(&degi[dst[e]], 1);
    }
}

__global__ void k_norm(const int* __restrict__ dego, const int* __restrict__ degi,
                       float* __restrict__ wout, float* __restrict__ win) {
    int n = blockIdx.x * 256 + threadIdx.x;
    if (n < NN) {
        wout[n] = rsqrtf(fmaxf((float)dego[n], 1.f));
        win[n]  = rsqrtf(fmaxf((float)degi[n], 1.f));
    }
}

// exclusive scan of in-degrees -> in_off[0..NN], one block of 512 threads
__global__ void k_scan(const int* __restrict__ degi, int* __restrict__ ioff) {
    __shared__ int part[512];
    int t = threadIdx.x;
    int base = t * 4;
    int v[4]; int s = 0;
#pragma unroll
    for (int i = 0; i < 4; i++) {
        int idx = base + i;
        v[i] = (idx < NN) ? degi[idx] : 0;
        s += v[i];
    }
    part[t] = s;
    __syncthreads();
    for (int o = 1; o < 512; o <<= 1) {
        int x = 0;
        if (t >= o) x = part[t - o];
        __syncthreads();
        part[t] += x;
        __syncthreads();
    }
    int run = (t == 0) ? 0 : part[t - 1];
#pragma unroll
    for (int i = 0; i < 4; i++) {
        int idx = base + i;
        if (idx <= NN) ioff[idx] = run;
        run += v[i];
    }
}

__global__ void k_fill(const int* __restrict__ src, const int* __restrict__ dst,
                       const float* __restrict__ wout, const float* __restrict__ win,
                       const int* __restrict__ ioff, int* __restrict__ cursor,
                       int* __restrict__ csrc, float* __restrict__ csrw) {
    int e = blockIdx.x * 256 + threadIdx.x;
    if (e < E_) {
        int d = dst[e];
        int s = src[e];
        int p = atomicAdd(&cursor[d], 1);
        int i = ioff[d] + p;
        csrc[i] = s;
        csrw[i] = wout[s] * win[d];
    }
}

// transpose W (256x256) into bf16 hi/lo planes: T*[n*256+k] = split(W[k*256+n])
__global__ __launch_bounds__(256) void k_prepw(const float* __restrict__ W,
                                               u16* __restrict__ Th,
                                               u16* __restrict__ Tl) {
    int n = blockIdx.x, k = threadIdx.x;
    float w = W[(size_t)k * 256 + n];
    u16 h = f2bf(w);
    Th[n * 256 + k] = h;
    Tl[n * 256 + k] = f2bf(w - bf2f(h));
}

// layer 0: agg over scalar node feature, expand through W0 (1x256) + b0, relu
__global__ __launch_bounds__(64) void k_layer0(
        const float* __restrict__ inp, const int* __restrict__ ioff,
        const int* __restrict__ csrc, const float* __restrict__ csrw,
        const float* __restrict__ W0, const float* __restrict__ b0,
        float* __restrict__ xout, int b0g) {
    int n = blockIdx.x, bl = blockIdx.y, t = threadIdx.x;
    int e0 = ioff[n], e1 = ioff[n + 1];
    const float* row = inp + (size_t)(b0g + bl) * ROWST + CIN;
    float a = 0.f;
    for (int i = e0; i < e1; i++) a += csrw[i] * row[csrc[i]];
    float4 w  = *reinterpret_cast<const float4*>(&W0[t * 4]);
    float4 bb = *reinterpret_cast<const float4*>(&b0[t * 4]);
    float4 o;
    o.x = fmaxf(a * w.x + bb.x, 0.f);
    o.y = fmaxf(a * w.y + bb.y, 0.f);
    o.z = fmaxf(a * w.z + bb.z, 0.f);
    o.w = fmaxf(a * w.w + bb.w, 0.f);
    *reinterpret_cast<float4*>(&xout[((size_t)bl * NN + n) * C_ + t * 4]) = o;
}

// layers 1,2 aggregation: xout[bl,n,:] = sum_e w_e * xin[bl,src_e,:]
// XCD-locality swizzle: each XCD owns QB consecutive batch elems, walks nodes
// sequentially -> the active x[bl] slice (2 MB) stays resident in that XCD's L2.
__global__ __launch_bounds__(64) void k_agg(
        const float* __restrict__ xin, const int* __restrict__ ioff,
        const int* __restrict__ csrc, const float* __restrict__ csrw,
        float* __restrict__ xout, int QB) {
    int n, bl;
    if (QB > 0) {
        int l = blockIdx.x + NN * blockIdx.y;   // HW linear workgroup id (x fastest)
        int xcd = l & 7;
        int slot = l >> 3;
        int q = slot / NN;
        bl = xcd * QB + q;
        n  = slot - q * NN;
    } else {
        n = blockIdx.x; bl = blockIdx.y;
    }
    int t = threadIdx.x;
    int e0 = ioff[n], e1 = ioff[n + 1];
    const float* xb = xin + (size_t)bl * NN * C_;
    float4 acc = {0.f, 0.f, 0.f, 0.f};
    for (int i = e0; i < e1; i++) {
        int s   = csrc[i];
        float w = csrw[i];
        float4 v = *reinterpret_cast<const float4*>(&xb[(size_t)s * C_ + t * 4]);
        acc.x += w * v.x; acc.y += w * v.y; acc.z += w * v.z; acc.w += w * v.w;
    }
    *reinterpret_cast<float4*>(&xout[((size_t)bl * NN + n) * C_ + t * 4]) = acc;
}

// ---------------- MFMA GEMM: C = relu(A @ W + bias) ----------------
// A: (M,256) fp32 row-major. W given as transposed bf16 hi/lo planes
// WT[n*256+k]. 3-pass hi/lo split: Ah*Bh + Al*Bh + Ah*Bl (~2^-17 rel err).
// mfma_f32_16x16x32_bf16 fragment layout (m92/m97-verified):
//   A: lane l holds A[l&15][(l>>4)*8 + j], j=0..7 (contiguous 8 in k)
//   B: lane l holds B[(l>>4)*8 + j][l&15]  == WT[l&15][(l>>4)*8 + j]
//   C/D: col = lane&15, row = (lane>>4)*4 + reg
#define GM 128
#define GN 64
#define GK 32
#define LDP 56   // padded u16 row stride: 112 B = 16B-aligned, 2-way bank max

__global__ __launch_bounds__(256) void k_gemm_mfma(
        const float* __restrict__ A, const u16* __restrict__ WTh,
        const u16* __restrict__ WTl, const float* __restrict__ bias,
        float* __restrict__ Cout) {
    __shared__ u16 Ah[GM * LDP];
    __shared__ u16 Al[GM * LDP];
    __shared__ u16 Bh[GN * LDP];
    __shared__ u16 Bl[GN * LDP];
    int tid  = threadIdx.x;
    int lane = tid & 63, wave = tid >> 6;
    int wm = wave >> 1, wn = wave & 1;
    int n0 = blockIdx.x * GN;
    int m0 = blockIdx.y * GM;
    int blk = lane >> 4, rr = lane & 15;

    f32x4 acc[4][2] = {};

    for (int k0 = 0; k0 < 256; k0 += GK) {
        // stage A tile: 128 rows x 32 k fp32 -> bf16 hi/lo.  1024 float4s.
#pragma unroll
        for (int q = 0; q < 4; q++) {
            int f   = tid + 256 * q;
            int row = f >> 3, c4 = f & 7;
            float4 av = *reinterpret_cast<const float4*>(
                &A[(size_t)(m0 + row) * 256 + k0 + c4 * 4]);
            float vv[4] = {av.x, av.y, av.z, av.w};
            unsigned hp0, hp1, lp0, lp1;
            {
                u16 h0 = f2bf(vv[0]), h1 = f2bf(vv[1]), h2 = f2bf(vv[2]), h3 = f2bf(vv[3]);
                u16 l0 = f2bf(vv[0] - bf2f(h0)), l1 = f2bf(vv[1] - bf2f(h1));
                u16 l2 = f2bf(vv[2] - bf2f(h2)), l3 = f2bf(vv[3] - bf2f(h3));
                hp0 = (unsigned)h0 | ((unsigned)h1 << 16);
                hp1 = (unsigned)h2 | ((unsigned)h3 << 16);
                lp0 = (unsigned)l0 | ((unsigned)l1 << 16);
                lp1 = (unsigned)l2 | ((unsigned)l3 << 16);
            }
            uint2 hw; hw.x = hp0; hw.y = hp1;
            uint2 lw; lw.x = lp0; lw.y = lp1;
            *reinterpret_cast<uint2*>(&Ah[row * LDP + c4 * 4]) = hw;
            *reinterpret_cast<uint2*>(&Al[row * LDP + c4 * 4]) = lw;
        }
        // stage B tile: 64 rows (n) x 32 k bf16 hi/lo (already bf16 in global)
        {
            int row = tid >> 2, seg = tid & 3;
            const uint4* gh = reinterpret_cast<const uint4*>(
                &WTh[(size_t)(n0 + row) * 256 + k0 + seg * 8]);
            const uint4* gl = reinterpret_cast<const uint4*>(
                &WTl[(size_t)(n0 + row) * 256 + k0 + seg * 8]);
            *reinterpret_cast<uint4*>(&Bh[row * LDP + seg * 8]) = *gh;
            *reinterpret_cast<uint4*>(&Bl[row * LDP + seg * 8]) = *gl;
        }
        __syncthreads();

        short8 a_h[4], a_l[4], b_h[2], b_l[2];
#pragma unroll
        for (int mr = 0; mr < 4; mr++) {
            int row = wm * 64 + mr * 16 + rr;
            a_h[mr] = *reinterpret_cast<const short8*>(&Ah[row * LDP + blk * 8]);
            a_l[mr] = *reinterpret_cast<const short8*>(&Al[row * LDP + blk * 8]);
        }
#pragma unroll
        for (int nr = 0; nr < 2; nr++) {
            int row = wn * 32 + nr * 16 + rr;
            b_h[nr] = *reinterpret_cast<const short8*>(&Bh[row * LDP + blk * 8]);
            b_l[nr] = *reinterpret_cast<const short8*>(&Bl[row * LDP + blk * 8]);
        }
#pragma unroll
        for (int mr = 0; mr < 4; mr++)
#pragma unroll
            for (int nr = 0; nr < 2; nr++) {
                acc[mr][nr] = __builtin_amdgcn_mfma_f32_16x16x32_bf16(
                    a_h[mr], b_h[nr], acc[mr][nr], 0, 0, 0);
                acc[mr][nr] = __builtin_amdgcn_mfma_f32_16x16x32_bf16(
                    a_l[mr], b_h[nr], acc[mr][nr], 0, 0, 0);
                acc[mr][nr] = __builtin_amdgcn_mfma_f32_16x16x32_bf16(
                    a_h[mr], b_l[nr], acc[mr][nr], 0, 0, 0);
            }
        __syncthreads();
    }

    // epilogue: bias + relu, fp32 store
#pragma unroll
    for (int nr = 0; nr < 2; nr++) {
        int col = n0 + wn * 32 + nr * 16 + rr;
        float bs = bias[col];
#pragma unroll
        for (int mr = 0; mr < 4; mr++) {
            int rbase = m0 + wm * 64 + mr * 16 + blk * 4;
#pragma unroll
            for (int j = 0; j < 4; j++) {
                Cout[(size_t)(rbase + j) * 256 + col] = fmaxf(acc[mr][nr][j] + bs, 0.f);
            }
        }
    }
}

// pooling partials: 8 splits of 250 rows  (chunk-local b)
__global__ __launch_bounds__(256) void k_pool(
        const float* __restrict__ x, float* __restrict__ psum, float* __restrict__ pmax) {
    int bl = blockIdx.x, s = blockIdx.y, c = threadIdx.x;
    const float* xb = x + (size_t)bl * NN * C_;
    int n0 = s * 250;
    float sum = 0.f, mx = -INFINITY;
    for (int i = 0; i < 250; i++) {
        float v = xb[(size_t)(n0 + i) * C_ + c];
        sum += v;
        mx = fmaxf(mx, v);
    }
    psum[((size_t)bl * 8 + s) * C_ + c] = sum;
    pmax[((size_t)bl * 8 + s) * C_ + c] = mx;
}

__global__ __launch_bounds__(256) void k_pool_combine(
        const float* __restrict__ psum, const float* __restrict__ pmax,
        float* __restrict__ hg, int b0g) {
    int bl = blockIdx.x, c = threadIdx.x;
    float s = 0.f, m = -INFINITY;
#pragma unroll
    for (int i = 0; i < 8; i++) {
        s += psum[((size_t)bl * 8 + i) * C_ + c];
        m = fmaxf(m, pmax[((size_t)bl * 8 + i) * C_ + c]);
    }
    size_t b = b0g + bl;
    hg[b * 512 + c]       += fmaxf(s * (1.f / (float)NN), 0.f);
    hg[b * 512 + 256 + c] += fmaxf(m, 0.f);
}

__global__ __launch_bounds__(128) void k_embed(
        const float* __restrict__ inp, const float* __restrict__ We,
        float* __restrict__ emb) {
    int b = blockIdx.x, c = threadIdx.x;
    const float* row = inp + (size_t)b * ROWST;
    float a = 0.f;
    for (int k = 0; k < CIN; k++) a += row[k] * We[k * CEMB + c];
    emb[b * CEMB + c] = fmaxf(a, 0.f);
}

__global__ __launch_bounds__(512) void k_mlp1(
        const float* __restrict__ emb, const float* __restrict__ hg,
        const float* __restrict__ Wh1, const float* __restrict__ bh1,
        float* __restrict__ h1) {
    __shared__ float fus[FUSD];
    int b = blockIdx.x, j = threadIdx.x;
    if (j < CEMB) fus[j] = emb[b * CEMB + j];
    fus[CEMB + j] = hg[(size_t)b * 512 + j];
    __syncthreads();
    float a = bh1[j];
    for (int k = 0; k < FUSD; k++) a += fus[k] * Wh1[(size_t)k * HAZ1 + j];
    h1[(size_t)b * HAZ1 + j] = fmaxf(a, 0.f);
}

__global__ __launch_bounds__(256) void k_mlp2(
        const float* __restrict__ h1, const float* __restrict__ Wh2,
        const float* __restrict__ bh2, float* __restrict__ h2) {
    __shared__ float f2[HAZ1];
    int b = blockIdx.x, j = threadIdx.x;
    f2[j]       = h1[(size_t)b * HAZ1 + j];
    f2[256 + j] = h1[(size_t)b * HAZ1 + 256 + j];
    __syncthreads();
    float a = bh2[j];
    for (int k = 0; k < HAZ1; k++) a += f2[k] * Wh2[(size_t)k * HAZ2 + j];
    h2[(size_t)b * HAZ2 + j] = fmaxf(a, 0.f);
}

__global__ __launch_bounds__(256) void k_out(
        const float* __restrict__ h2, const float* __restrict__ Wh3,
        float* __restrict__ out) {
    __shared__ float red[256];
    int b = blockIdx.x, t = threadIdx.x;
    red[t] = h2[(size_t)b * HAZ2 + t] * Wh3[t];
    __syncthreads();
    for (int o = 128; o > 0; o >>= 1) {
        if (t < o) red[t] += red[t + o];
        __syncthreads();
    }
    if (t == 0) out[b] = red[0];
}

// ---------------- launch ----------------
extern "C" void kernel_launch(void* const* d_in, const int* in_sizes, int n_in,
                              void* d_out, int out_size, void* d_ws, size_t ws_size,
                              hipStream_t stream) {
    const float* inp = (const float*)d_in[0];
    const int*   src = (const int*)d_in[1];
    const int*   dst = (const int*)d_in[2];
    const float* W0  = (const float*)d_in[3];
    const float* b0  = (const float*)d_in[4];
    const float* W1  = (const float*)d_in[5];
    const float* b1  = (const float*)d_in[6];
    const float* W2  = (const float*)d_in[7];
    const float* b2  = (const float*)d_in[8];
    const float* We  = (const float*)d_in[9];
    const float* Wh1 = (const float*)d_in[10];
    const float* bh1 = (const float*)d_in[11];
    const float* Wh2 = (const float*)d_in[12];
    const float* bh2 = (const float*)d_in[13];
    const float* Wh3 = (const float*)d_in[14];
    float* out = (float*)d_out;

    char* ws = (char*)d_ws;
    int*   dego = (int*)(ws + OFF_DEGO);
    int*   degi = (int*)(ws + OFF_DEGI);
    int*   cur  = (int*)(ws + OFF_CUR);
    float* wout = (float*)(ws + OFF_WOUT);
    float* win  = (float*)(ws + OFF_WIN);
    int*   ioff = (int*)(ws + OFF_IOFF);
    int*   csrc = (int*)(ws + OFF_CSRC);
    float* csrw = (float*)(ws + OFF_CSRW);
    float* hg   = (float*)(ws + OFF_HG);
    float* emb  = (float*)(ws + OFF_EMB);
    float* h1   = (float*)(ws + OFF_H1);
    float* h2   = (float*)(ws + OFF_H2);
    float* psum = (float*)(ws + OFF_PSUM);
    float* pmax = (float*)(ws + OFF_PMAX);
    u16*   wt1h = (u16*)(ws + OFF_WT1H);
    u16*   wt1l = (u16*)(ws + OFF_WT1L);
    u16*   wt2h = (u16*)(ws + OFF_WT2H);
    u16*   wt2l = (u16*)(ws + OFF_WT2L);

    // ---- choose batch-chunk size CB so the footprint fits ws_size ----
    // need = OFF_XA + 2 * CB * SZ_B1.  CB in {128,64,32,16,8} (mult of 8:
    // keeps CB*2000 %128==0 for GEMM tiles and enables the XCD swizzle).
    int CB = 128;
    while (CB > 8 && OFF_XA + 2ull * (size_t)CB * SZ_B1 > ws_size) CB >>= 1;
    int nchunk = B_ / CB;
    int QB = CB / 8;

    float* xA = (float*)(ws + OFF_XA);
    float* xB = (float*)(ws + OFF_XA + (size_t)CB * SZ_B1);

    // zero: deg_out/deg_in/cursor (6000 ints) and hg (65536 floats)
    k_zero<<<dim3((6000 + 255) / 256), 256, 0, stream>>>((float*)dego, 6000);
    k_zero<<<dim3((65536 + 255) / 256), 256, 0, stream>>>(hg, 65536);

    // graph normalization + CSR build + weight transpose/split
    k_deg<<<dim3((E_ + 255) / 256), 256, 0, stream>>>(src, dst, dego, degi);
    k_norm<<<dim3((NN + 255) / 256), 256, 0, stream>>>(dego, degi, wout, win);
    k_scan<<<1, 512, 0, stream>>>(degi, ioff);
    k_fill<<<dim3((E_ + 255) / 256), 256, 0, stream>>>(src, dst, wout, win, ioff, cur, csrc, csrw);
    k_prepw<<<256, 256, 0, stream>>>(W1, wt1h, wt1l);
    k_prepw<<<256, 256, 0, stream>>>(W2, wt2h, wt2l);

    dim3 gridNB(NN, CB);
    dim3 gridGemm(C_ / GN, (CB * NN) / GM);
    dim3 gridPool(CB, 8);

    for (int c = 0; c < nchunk; ++c) {
        int b0g = c * CB;

        // layer 0: agg (C=1) + expand -> xA
        k_layer0<<<gridNB, 64, 0, stream>>>(inp, ioff, csrc, csrw, W0, b0, xA, b0g);
        k_pool<<<gridPool, 256, 0, stream>>>(xA, psum, pmax);
        k_pool_combine<<<CB, 256, 0, stream>>>(psum, pmax, hg, b0g);

        // layer 1: agg xA -> xB, gemm xB @ W1 -> xA
        k_agg<<<gridNB, 64, 0, stream>>>(xA, ioff, csrc, csrw, xB, QB);
        k_gemm_mfma<<<gridGemm, 256, 0, stream>>>(xB, wt1h, wt1l, b1, xA);
        k_pool<<<gridPool, 256, 0, stream>>>(xA, psum, pmax);
        k_pool_combine<<<CB, 256, 0, stream>>>(psum, pmax, hg, b0g);

        // layer 2: agg xA -> xB, gemm xB @ W2 -> xA
        k_agg<<<gridNB, 64, 0, stream>>>(xA, ioff, csrc, csrw, xB, QB);
        k_gemm_mfma<<<gridGemm, 256, 0, stream>>>(xB, wt2h, wt2l, b2, xA);
        k_pool<<<gridPool, 256, 0, stream>>>(xA, psum, pmax);
        k_pool_combine<<<CB, 256, 0, stream>>>(psum, pmax, hg, b0g);
    }

    // head
    k_embed<<<B_, 128, 0, stream>>>(inp, We, emb);
    k_mlp1<<<B_, 512, 0, stream>>>(emb, hg, Wh1, bh1, h1);
    k_mlp2<<<B_, 256, 0, stream>>>(h1, Wh2, bh2, h2);
    k_out<<<B_, 256, 0, stream>>>(h2, Wh3, out);
}

// Round 4
// 1120.074 us; speedup vs baseline: 2.4498x; 1.3830x over previous
//
#include <hip/hip_runtime.h>
#include <hip/hip_bf16.h>

// ---------------- problem constants ----------------
#define B_    128
#define NN    2000
#define C_    256
#define E_    64000
#define CIN   64
#define ROWST 2064   // CIN + NN
#define CEMB  128
#define HAZ1  512
#define HAZ2  256
#define FUSD  640    // CEMB + 2*C_

typedef unsigned short u16;
typedef __attribute__((ext_vector_type(8))) short short8;
typedef __attribute__((ext_vector_type(4))) float f32x4;

// ---------------- workspace layout (bytes) ----------------
static constexpr size_t OFF_DEGO = 0;        // int[2000]
static constexpr size_t OFF_DEGI = 8000;     // int[2000]
static constexpr size_t OFF_CUR  = 16000;    // int[2000]
static constexpr size_t OFF_WOUT = 24000;    // float[2000]
static constexpr size_t OFF_WIN  = 32000;    // float[2000]
static constexpr size_t OFF_IOFF = 40000;    // int[2001] (padded)
static constexpr size_t OFF_CSRC = 48192;    // int[64000]
static constexpr size_t OFF_CSRW = 304192;   // float[64000]
static constexpr size_t OFF_HG   = 560192;   // float[128*512]           -> 822336
static constexpr size_t OFF_EMB  = 822336;   // float[128*128]           -> 887872
static constexpr size_t OFF_H1   = 887872;   // float[128*512]           -> 1150016
static constexpr size_t OFF_H2   = 1150016;  // float[128*256]           -> 1281088
static constexpr size_t OFF_PSUM = 1281088;  // float[128*256]           -> 1412160
static constexpr size_t OFF_PMAX = 1412160;  // float[128*256]           -> 1543232
static constexpr size_t OFF_A    = 1543232;  // float[128*2000]          -> 2567232
static constexpr size_t OFF_WT1H = 2567232;  // u16[256*256]             -> 2698304
static constexpr size_t OFF_WT1L = 2698304;  //                          -> 2829376
static constexpr size_t OFF_WT2H = 2829376;  //                          -> 2960448
static constexpr size_t OFF_WT2L = 2960448;  //                          -> 3091520
static constexpr size_t OFF_XBUF = 4194304;  // xB fp32 [CB*NN*C_], then xA bf16 [CB*NN*C_]

// ---------------- bf16 helpers (RNE) ----------------
__device__ __forceinline__ u16 f2bf(float f) {
    union { float f; unsigned u; } v; v.f = f;
    unsigned u = v.u;
    unsigned r = (u + 0x7FFFu + ((u >> 16) & 1u)) >> 16;
    return (u16)r;
}
__device__ __forceinline__ float bf2f(u16 h) {
    union { unsigned u; float f; } v; v.u = ((unsigned)h) << 16;
    return v.f;
}

// ---------------- utility ----------------
__global__ void k_zero(float* p, int n) {
    int i = blockIdx.x * 256 + threadIdx.x;
    if (i < n) p[i] = 0.f;
}

__global__ void k_deg(const int* __restrict__ src, const int* __restrict__ dst,
                      int* __restrict__ dego, int* __restrict__ degi) {
    int e = blockIdx.x * 256 + threadIdx.x;
    if (e < E_) {
        atomicAdd(&dego[src[e]], 1);
        atomicAdd(&degi[dst[e]], 1);
    }
}

__global__ void k_norm(const int* __restrict__ dego, const int* __restrict__ degi,
                       float* __restrict__ wout, float* __restrict__ win) {
    int n = blockIdx.x * 256 + threadIdx.x;
    if (n < NN) {
        wout[n] = rsqrtf(fmaxf((float)dego[n], 1.f));
        win[n]  = rsqrtf(fmaxf((float)degi[n], 1.f));
    }
}

// exclusive scan of in-degrees -> in_off[0..NN], one block of 512 threads
__global__ void k_scan(const int* __restrict__ degi, int* __restrict__ ioff) {
    __shared__ int part[512];
    int t = threadIdx.x;
    int base = t * 4;
    int v[4]; int s = 0;
#pragma unroll
    for (int i = 0; i < 4; i++) {
        int idx = base + i;
        v[i] = (idx < NN) ? degi[idx] : 0;
        s += v[i];
    }
    part[t] = s;
    __syncthreads();
    for (int o = 1; o < 512; o <<= 1) {
        int x = 0;
        if (t >= o) x = part[t - o];
        __syncthreads();
        part[t] += x;
        __syncthreads();
    }
    int run = (t == 0) ? 0 : part[t - 1];
#pragma unroll
    for (int i = 0; i < 4; i++) {
        int idx = base + i;
        if (idx <= NN) ioff[idx] = run;
        run += v[i];
    }
}

__global__ void k_fill(const int* __restrict__ src, const int* __restrict__ dst,
                       const float* __restrict__ wout, const float* __restrict__ win,
                       const int* __restrict__ ioff, int* __restrict__ cursor,
                       int* __restrict__ csrc, float* __restrict__ csrw) {
    int e = blockIdx.x * 256 + threadIdx.x;
    if (e < E_) {
        int d = dst[e];
        int s = src[e];
        int p = atomicAdd(&cursor[d], 1);
        int i = ioff[d] + p;
        csrc[i] = s;
        csrw[i] = wout[s] * win[d];
    }
}

// transpose W (256x256) into bf16 hi/lo planes: T*[n*256+k] = split(W[k*256+n])
__global__ __launch_bounds__(256) void k_prepw(const float* __restrict__ W,
                                               u16* __restrict__ Th,
                                               u16* __restrict__ Tl) {
    int n = blockIdx.x, k = threadIdx.x;
    float w = W[(size_t)k * 256 + n];
    u16 h = f2bf(w);
    Th[n * 256 + k] = h;
    Tl[n * 256 + k] = f2bf(w - bf2f(h));
}

// scalar graph conv of the input node feature: a[b,n] = sum_e csrw * inp_x[b,src]
// one thread per (b, n); all B at once.
__global__ __launch_bounds__(64) void k_agg_scalar(
        const float* __restrict__ inp, const int* __restrict__ ioff,
        const int* __restrict__ csrc, const float* __restrict__ csrw,
        float* __restrict__ a) {
    int n = blockIdx.x * 64 + threadIdx.x;
    int b = blockIdx.y;
    if (n >= NN) return;
    const float* row = inp + (size_t)b * ROWST + CIN;
    int e0 = ioff[n], e1 = ioff[n + 1];
    float acc = 0.f;
    for (int i = e0; i < e1; i++) acc += csrw[i] * row[csrc[i]];
    a[(size_t)b * NN + n] = acc;
}

// layer-0 pooling straight from a: x0[b,n,c] = relu(a*W0[c]+b0[c])
__global__ __launch_bounds__(256) void k_pool0(
        const float* __restrict__ a, const float* __restrict__ W0,
        const float* __restrict__ b0, float* __restrict__ hg) {
    int b = blockIdx.x, c = threadIdx.x;
    float w0c = W0[c], b0c = b0[c];
    const float* ab = a + (size_t)b * NN;
    float s = 0.f, mx = 0.f;
    for (int n = 0; n < NN; n++) {
        float v = fmaxf(fmaf(ab[n], w0c, b0c), 0.f);
        s += v;
        mx = fmaxf(mx, v);
    }
    hg[(size_t)b * 512 + c]       += s * (1.f / (float)NN);
    hg[(size_t)b * 512 + 256 + c] += mx;
}

// fused layer-0-expand + layer-1 aggregation:
// xout[bl,n,c] = sum_e csrw[e] * relu(a[bl,src]*W0[c]+b0[c])
__global__ __launch_bounds__(64) void k_agg_l1(
        const float* __restrict__ a, const int* __restrict__ ioff,
        const int* __restrict__ csrc, const float* __restrict__ csrw,
        const float* __restrict__ W0, const float* __restrict__ b0,
        float* __restrict__ xout, int b0g) {
    int n = blockIdx.x, bl = blockIdx.y, t = threadIdx.x;
    int e0 = ioff[n], e1 = ioff[n + 1];
    const float* ab = a + (size_t)(b0g + bl) * NN;
    float4 w  = *reinterpret_cast<const float4*>(&W0[t * 4]);
    float4 bb = *reinterpret_cast<const float4*>(&b0[t * 4]);
    float4 acc = {0.f, 0.f, 0.f, 0.f};
    for (int i = e0; i < e1; i++) {
        float av = ab[csrc[i]];
        float we = csrw[i];
        acc.x = fmaf(fmaxf(fmaf(av, w.x, bb.x), 0.f), we, acc.x);
        acc.y = fmaf(fmaxf(fmaf(av, w.y, bb.y), 0.f), we, acc.y);
        acc.z = fmaf(fmaxf(fmaf(av, w.z, bb.z), 0.f), we, acc.z);
        acc.w = fmaf(fmaxf(fmaf(av, w.w, bb.w), 0.f), we, acc.w);
    }
    *reinterpret_cast<float4*>(&xout[((size_t)bl * NN + n) * C_ + t * 4]) = acc;
}

// layer-2 aggregation from bf16 x: xout[bl,n,:] = sum_e w_e * bf2f(xin[bl,src,:])
// XCD-locality swizzle (verified round 3: FETCH 1.23GB -> ideal)
__global__ __launch_bounds__(64) void k_agg_bf(
        const u16* __restrict__ xin, const int* __restrict__ ioff,
        const int* __restrict__ csrc, const float* __restrict__ csrw,
        float* __restrict__ xout, int QB) {
    int n, bl;
    {
        int l = blockIdx.x + NN * blockIdx.y;   // HW linear workgroup id (x fastest)
        int xcd = l & 7;
        int slot = l >> 3;
        int q = slot / NN;
        bl = xcd * QB + q;
        n  = slot - q * NN;
    }
    int t = threadIdx.x;
    int e0 = ioff[n], e1 = ioff[n + 1];
    const u16* xb = xin + (size_t)bl * NN * C_;
    float4 acc = {0.f, 0.f, 0.f, 0.f};
    for (int i = e0; i < e1; i++) {
        int s   = csrc[i];
        float w = csrw[i];
        ushort4 v = *reinterpret_cast<const ushort4*>(&xb[(size_t)s * C_ + t * 4]);
        acc.x = fmaf(bf2f(v.x), w, acc.x);
        acc.y = fmaf(bf2f(v.y), w, acc.y);
        acc.z = fmaf(bf2f(v.z), w, acc.z);
        acc.w = fmaf(bf2f(v.w), w, acc.w);
    }
    *reinterpret_cast<float4*>(&xout[((size_t)bl * NN + n) * C_ + t * 4]) = acc;
}

// ---------------- MFMA GEMM with fused pooling ----------------
// C = relu(A @ W + bias); pool (sum,max) per (bl, col) into psum/pmax atomics.
// OUT: 0 = pool only (no C write), 1 = write C as bf16.
// mfma_f32_16x16x32_bf16 layout (m92/m97-verified):
//   A: lane l holds A[l&15][(l>>4)*8+j]; B: lane l holds WT[l&15][(l>>4)*8+j]
//   C/D: col = lane&15, row = (lane>>4)*4 + reg
#define GM 128
#define GN 64
#define GK 32
#define LDP 56   // padded u16 row stride

template<int OUT>
__global__ __launch_bounds__(256) void k_gemm_mfma(
        const float* __restrict__ A, const u16* __restrict__ WTh,
        const u16* __restrict__ WTl, const float* __restrict__ bias,
        u16* __restrict__ Cbf, float* __restrict__ psum, float* __restrict__ pmax) {
    __shared__ u16 Ah[GM * LDP];
    __shared__ u16 Al[GM * LDP];
    __shared__ u16 Bh[GN * LDP];
    __shared__ u16 Bl[GN * LDP];
    __shared__ float lsum[2][2][GN];
    __shared__ float lmax[2][2][GN];
    int tid  = threadIdx.x;
    int lane = tid & 63, wave = tid >> 6;
    int wm = wave >> 1, wn = wave & 1;
    int n0 = blockIdx.x * GN;
    int m0 = blockIdx.y * GM;
    int blk = lane >> 4, rr = lane & 15;

    f32x4 acc[4][2] = {};

    for (int k0 = 0; k0 < 256; k0 += GK) {
#pragma unroll
        for (int q = 0; q < 4; q++) {
            int f   = tid + 256 * q;
            int row = f >> 3, c4 = f & 7;
            float4 av = *reinterpret_cast<const float4*>(
                &A[(size_t)(m0 + row) * 256 + k0 + c4 * 4]);
            float vv[4] = {av.x, av.y, av.z, av.w};
            u16 h0 = f2bf(vv[0]), h1 = f2bf(vv[1]), h2 = f2bf(vv[2]), h3 = f2bf(vv[3]);
            u16 l0 = f2bf(vv[0] - bf2f(h0)), l1 = f2bf(vv[1] - bf2f(h1));
            u16 l2 = f2bf(vv[2] - bf2f(h2)), l3 = f2bf(vv[3] - bf2f(h3));
            uint2 hw; hw.x = (unsigned)h0 | ((unsigned)h1 << 16);
            hw.y = (unsigned)h2 | ((unsigned)h3 << 16);
            uint2 lw; lw.x = (unsigned)l0 | ((unsigned)l1 << 16);
            lw.y = (unsigned)l2 | ((unsigned)l3 << 16);
            *reinterpret_cast<uint2*>(&Ah[row * LDP + c4 * 4]) = hw;
            *reinterpret_cast<uint2*>(&Al[row * LDP + c4 * 4]) = lw;
        }
        {
            int row = tid >> 2, seg = tid & 3;
            const uint4* gh = reinterpret_cast<const uint4*>(
                &WTh[(size_t)(n0 + row) * 256 + k0 + seg * 8]);
            const uint4* gl = reinterpret_cast<const uint4*>(
                &WTl[(size_t)(n0 + row) * 256 + k0 + seg * 8]);
            *reinterpret_cast<uint4*>(&Bh[row * LDP + seg * 8]) = *gh;
            *reinterpret_cast<uint4*>(&Bl[row * LDP + seg * 8]) = *gl;
        }
        __syncthreads();

        short8 a_h[4], a_l[4], b_h[2], b_l[2];
#pragma unroll
        for (int mr = 0; mr < 4; mr++) {
            int row = wm * 64 + mr * 16 + rr;
            a_h[mr] = *reinterpret_cast<const short8*>(&Ah[row * LDP + blk * 8]);
            a_l[mr] = *reinterpret_cast<const short8*>(&Al[row * LDP + blk * 8]);
        }
#pragma unroll
        for (int nr = 0; nr < 2; nr++) {
            int row = wn * 32 + nr * 16 + rr;
            b_h[nr] = *reinterpret_cast<const short8*>(&Bh[row * LDP + blk * 8]);
            b_l[nr] = *reinterpret_cast<const short8*>(&Bl[row * LDP + blk * 8]);
        }
#pragma unroll
        for (int mr = 0; mr < 4; mr++)
#pragma unroll
            for (int nr = 0; nr < 2; nr++) {
                acc[mr][nr] = __builtin_amdgcn_mfma_f32_16x16x32_bf16(
                    a_h[mr], b_h[nr], acc[mr][nr], 0, 0, 0);
                acc[mr][nr] = __builtin_amdgcn_mfma_f32_16x16x32_bf16(
                    a_l[mr], b_h[nr], acc[mr][nr], 0, 0, 0);
                acc[mr][nr] = __builtin_amdgcn_mfma_f32_16x16x32_bf16(
                    a_h[mr], b_l[nr], acc[mr][nr], 0, 0, 0);
            }
        __syncthreads();
    }

    // epilogue: bias + relu, optional bf16 store, fused (sum,max) pool
    int bl0   = m0 / NN;
    int split = (bl0 + 1) * NN - m0;   // rows >= split belong to bl0+1

    float s_lo[2] = {0.f, 0.f}, s_hi[2] = {0.f, 0.f};
    float m_lo[2] = {0.f, 0.f}, m_hi[2] = {0.f, 0.f};
#pragma unroll
    for (int nr = 0; nr < 2; nr++) {
        int col = n0 + wn * 32 + nr * 16 + rr;
        float bs = bias[col];
#pragma unroll
        for (int mr = 0; mr < 4; mr++) {
            int rl_base = wm * 64 + mr * 16 + blk * 4;
#pragma unroll
            for (int j = 0; j < 4; j++) {
                float v = fmaxf(acc[mr][nr][j] + bs, 0.f);
                if (OUT == 1)
                    Cbf[(size_t)(m0 + rl_base + j) * 256 + col] = f2bf(v);
                bool second = (rl_base + j) >= split;
                s_lo[nr] += second ? 0.f : v;
                s_hi[nr] += second ? v : 0.f;
                m_lo[nr] = second ? m_lo[nr] : fmaxf(m_lo[nr], v);
                m_hi[nr] = second ? fmaxf(m_hi[nr], v) : m_hi[nr];
            }
        }
    }
#pragma unroll
    for (int nr = 0; nr < 2; nr++) {
        s_lo[nr] += __shfl_xor(s_lo[nr], 16); s_lo[nr] += __shfl_xor(s_lo[nr], 32);
        s_hi[nr] += __shfl_xor(s_hi[nr], 16); s_hi[nr] += __shfl_xor(s_hi[nr], 32);
        m_lo[nr] = fmaxf(m_lo[nr], __shfl_xor(m_lo[nr], 16));
        m_lo[nr] = fmaxf(m_lo[nr], __shfl_xor(m_lo[nr], 32));
        m_hi[nr] = fmaxf(m_hi[nr], __shfl_xor(m_hi[nr], 16));
        m_hi[nr] = fmaxf(m_hi[nr], __shfl_xor(m_hi[nr], 32));
    }
    if (lane < 16) {
#pragma unroll
        for (int nr = 0; nr < 2; nr++) {
            int cl = wn * 32 + nr * 16 + lane;
            lsum[0][wm][cl] = s_lo[nr];
            lsum[1][wm][cl] = s_hi[nr];
            lmax[0][wm][cl] = m_lo[nr];
            lmax[1][wm][cl] = m_hi[nr];
        }
    }
    __syncthreads();
    if (tid < 128) {
        int seg = tid >> 6, cl = tid & 63;
        if (!(seg == 1 && split >= GM)) {
            float s = lsum[seg][0][cl] + lsum[seg][1][cl];
            float m = fmaxf(lmax[seg][0][cl], lmax[seg][1][cl]);
            int blx = bl0 + seg;
            atomicAdd(&psum[blx * C_ + n0 + cl], s);
            atomicMax((unsigned int*)&pmax[blx * C_ + n0 + cl], __float_as_uint(m));
        }
    }
}

// combine fused-pool results into hg, then reset psum/pmax for next use
__global__ __launch_bounds__(256) void k_pool_combine(
        float* __restrict__ psum, float* __restrict__ pmax,
        float* __restrict__ hg, int b0g) {
    int bl = blockIdx.x, c = threadIdx.x;
    float s = psum[bl * C_ + c];
    float m = pmax[bl * C_ + c];
    psum[bl * C_ + c] = 0.f;
    pmax[bl * C_ + c] = 0.f;
    size_t b = b0g + bl;
    hg[b * 512 + c]       += s * (1.f / (float)NN);
    hg[b * 512 + 256 + c] += m;
}

__global__ __launch_bounds__(128) void k_embed(
        const float* __restrict__ inp, const float* __restrict__ We,
        float* __restrict__ emb) {
    int b = blockIdx.x, c = threadIdx.x;
    const float* row = inp + (size_t)b * ROWST;
    float a = 0.f;
    for (int k = 0; k < CIN; k++) a += row[k] * We[k * CEMB + c];
    emb[b * CEMB + c] = fmaxf(a, 0.f);
}

__global__ __launch_bounds__(512) void k_mlp1(
        const float* __restrict__ emb, const float* __restrict__ hg,
        const float* __restrict__ Wh1, const float* __restrict__ bh1,
        float* __restrict__ h1) {
    __shared__ float fus[FUSD];
    int b = blockIdx.x, j = threadIdx.x;
    if (j < CEMB) fus[j] = emb[b * CEMB + j];
    fus[CEMB + j] = hg[(size_t)b * 512 + j];
    __syncthreads();
    float a = bh1[j];
    for (int k = 0; k < FUSD; k++) a += fus[k] * Wh1[(size_t)k * HAZ1 + j];
    h1[(size_t)b * HAZ1 + j] = fmaxf(a, 0.f);
}

__global__ __launch_bounds__(256) void k_mlp2(
        const float* __restrict__ h1, const float* __restrict__ Wh2,
        const float* __restrict__ bh2, float* __restrict__ h2) {
    __shared__ float f2[HAZ1];
    int b = blockIdx.x, j = threadIdx.x;
    f2[j]       = h1[(size_t)b * HAZ1 + j];
    f2[256 + j] = h1[(size_t)b * HAZ1 + 256 + j];
    __syncthreads();
    float a = bh2[j];
    for (int k = 0; k < HAZ1; k++) a += f2[k] * Wh2[(size_t)k * HAZ2 + j];
    h2[(size_t)b * HAZ2 + j] = fmaxf(a, 0.f);
}

__global__ __launch_bounds__(256) void k_out(
        const float* __restrict__ h2, const float* __restrict__ Wh3,
        float* __restrict__ out) {
    __shared__ float red[256];
    int b = blockIdx.x, t = threadIdx.x;
    red[t] = h2[(size_t)b * HAZ2 + t] * Wh3[t];
    __syncthreads();
    for (int o = 128; o > 0; o >>= 1) {
        if (t < o) red[t] += red[t + o];
        __syncthreads();
    }
    if (t == 0) out[b] = red[0];
}

// ---------------- launch ----------------
extern "C" void kernel_launch(void* const* d_in, const int* in_sizes, int n_in,
                              void* d_out, int out_size, void* d_ws, size_t ws_size,
                              hipStream_t stream) {
    const float* inp = (const float*)d_in[0];
    const int*   src = (const int*)d_in[1];
    const int*   dst = (const int*)d_in[2];
    const float* W0  = (const float*)d_in[3];
    const float* b0  = (const float*)d_in[4];
    const float* W1  = (const float*)d_in[5];
    const float* b1  = (const float*)d_in[6];
    const float* W2  = (const float*)d_in[7];
    const float* b2  = (const float*)d_in[8];
    const float* We  = (const float*)d_in[9];
    const float* Wh1 = (const float*)d_in[10];
    const float* bh1 = (const float*)d_in[11];
    const float* Wh2 = (const float*)d_in[12];
    const float* bh2 = (const float*)d_in[13];
    const float* Wh3 = (const float*)d_in[14];
    float* out = (float*)d_out;

    char* ws = (char*)d_ws;
    int*   dego = (int*)(ws + OFF_DEGO);
    int*   degi = (int*)(ws + OFF_DEGI);
    int*   cur  = (int*)(ws + OFF_CUR);
    float* wout = (float*)(ws + OFF_WOUT);
    float* win  = (float*)(ws + OFF_WIN);
    int*   ioff = (int*)(ws + OFF_IOFF);
    int*   csrc = (int*)(ws + OFF_CSRC);
    float* csrw = (float*)(ws + OFF_CSRW);
    float* hg   = (float*)(ws + OFF_HG);
    float* emb  = (float*)(ws + OFF_EMB);
    float* h1   = (float*)(ws + OFF_H1);
    float* h2   = (float*)(ws + OFF_H2);
    float* psum = (float*)(ws + OFF_PSUM);
    float* pmax = (float*)(ws + OFF_PMAX);
    float* avec = (float*)(ws + OFF_A);
    u16*   wt1h = (u16*)(ws + OFF_WT1H);
    u16*   wt1l = (u16*)(ws + OFF_WT1L);
    u16*   wt2h = (u16*)(ws + OFF_WT2H);
    u16*   wt2l = (u16*)(ws + OFF_WT2L);

    // ---- choose batch-chunk size CB ----
    // need = OFF_XBUF + CB*(NN*C_*4 [xB fp32] + NN*C_*2 [xA bf16])
    // CB multiple of 8: CB*NN % 128 == 0 and XCD swizzle divisibility.
    const size_t perb = (size_t)NN * C_ * 6;
    int CB = 128;
    while (CB > 8 && OFF_XBUF + (size_t)CB * perb > ws_size) CB >>= 1;
    int nchunk = B_ / CB;
    int QB = CB / 8;

    float* xB   = (float*)(ws + OFF_XBUF);                              // fp32 agg output
    u16*   xAbf = (u16*)(ws + OFF_XBUF + (size_t)CB * NN * C_ * 4);     // bf16 x1

    // zeros: deg counters (6000 ints), hg, psum+pmax (contiguous 65536 floats)
    k_zero<<<dim3((6000 + 255) / 256), 256, 0, stream>>>((float*)dego, 6000);
    k_zero<<<dim3((65536 + 255) / 256), 256, 0, stream>>>(hg, 65536);
    k_zero<<<dim3((65536 + 255) / 256), 256, 0, stream>>>(psum, 65536);

    // graph normalization + CSR build + weight transpose/split
    k_deg<<<dim3((E_ + 255) / 256), 256, 0, stream>>>(src, dst, dego, degi);
    k_norm<<<dim3((NN + 255) / 256), 256, 0, stream>>>(dego, degi, wout, win);
    k_scan<<<1, 512, 0, stream>>>(degi, ioff);
    k_fill<<<dim3((E_ + 255) / 256), 256, 0, stream>>>(src, dst, wout, win, ioff, cur, csrc, csrw);
    k_prepw<<<256, 256, 0, stream>>>(W1, wt1h, wt1l);
    k_prepw<<<256, 256, 0, stream>>>(W2, wt2h, wt2l);

    // scalar conv of input feature (all B), layer-0 pooling from it
    k_agg_scalar<<<dim3((NN + 63) / 64, B_), 64, 0, stream>>>(inp, ioff, csrc, csrw, avec);
    k_pool0<<<B_, 256, 0, stream>>>(avec, W0, b0, hg);

    dim3 gridNB(NN, CB);
    dim3 gridGemm(C_ / GN, (CB * NN) / GM);

    for (int c = 0; c < nchunk; ++c) {
        int b0g = c * CB;

        // layer 1: fused expand+agg -> xB; MFMA gemm + fused pool -> xA (bf16)
        k_agg_l1<<<gridNB, 64, 0, stream>>>(avec, ioff, csrc, csrw, W0, b0, xB, b0g);
        k_gemm_mfma<1><<<gridGemm, 256, 0, stream>>>(xB, wt1h, wt1l, b1, xAbf, psum, pmax);
        k_pool_combine<<<CB, 256, 0, stream>>>(psum, pmax, hg, b0g);

        // layer 2: bf16 gather agg -> xB; MFMA gemm, pool only (no C write)
        k_agg_bf<<<gridNB, 64, 0, stream>>>(xAbf, ioff, csrc, csrw, xB, QB);
        k_gemm_mfma<0><<<gridGemm, 256, 0, stream>>>(xB, wt2h, wt2l, b2, nullptr, psum, pmax);
        k_pool_combine<<<CB, 256, 0, stream>>>(psum, pmax, hg, b0g);
    }

    // head
    k_embed<<<B_, 128, 0, stream>>>(inp, We, emb);
    k_mlp1<<<B_, 512, 0, stream>>>(emb, hg, Wh1, bh1, h1);
    k_mlp2<<<B_, 256, 0, stream>>>(h1, Wh2, bh2, h2);
    k_out<<<B_, 256, 0, stream>>>(h2, Wh3, out);
}

// Round 5
// 730.184 us; speedup vs baseline: 3.7579x; 1.5340x over previous
//
#include <hip/hip_runtime.h>
#include <hip/hip_bf16.h>

// ---------------- problem constants ----------------
#define B_    128
#define NN    2000
#define C_    256
#define E_    64000
#define CIN   64
#define ROWST 2064   // CIN + NN
#define CEMB  128
#define HAZ1  512
#define HAZ2  256
#define FUSD  640    // CEMB + 2*C_

typedef unsigned short u16;
typedef __attribute__((ext_vector_type(8))) short short8;
typedef __attribute__((ext_vector_type(8))) unsigned short ush8;
typedef __attribute__((ext_vector_type(4))) float f32x4;

// ---------------- workspace layout (bytes) ----------------
static constexpr size_t OFF_DEGO = 0;        // int[2000]
static constexpr size_t OFF_DEGI = 8000;     // int[2000]
static constexpr size_t OFF_CUR  = 16000;    // int[2000]
static constexpr size_t OFF_WOUT = 24000;    // float[2000]
static constexpr size_t OFF_WIN  = 32000;    // float[2000]
static constexpr size_t OFF_IOFF = 40000;    // int[2001] (padded)
static constexpr size_t OFF_CSRC = 48192;    // int[64000]
static constexpr size_t OFF_CSRW = 304192;   // float[64000]
static constexpr size_t OFF_HG   = 560192;   // float[128*512]           -> 822336
static constexpr size_t OFF_EMB  = 822336;   // float[128*128]           -> 887872
static constexpr size_t OFF_H1   = 887872;   // float[128*512]           -> 1150016
static constexpr size_t OFF_H2   = 1150016;  // float[128*256]           -> 1281088
static constexpr size_t OFF_PSUM = 1281088;  // float[128*256]           -> 1412160
static constexpr size_t OFF_PMAX = 1412160;  // float[128*256]           -> 1543232
static constexpr size_t OFF_A    = 1543232;  // float[128*2000]          -> 2567232
static constexpr size_t OFF_WT1H = 2567232;  // u16[256*256]             -> 2698304
static constexpr size_t OFF_WT1L = 2698304;  //                          -> 2829376
static constexpr size_t OFF_WT2H = 2829376;  //                          -> 2960448
static constexpr size_t OFF_WT2L = 2960448;  //                          -> 3091520
static constexpr size_t OFF_XBUF = 4194304;  // xB bf16 [CB*NN*C_], then xA bf16 [CB*NN*C_]

// ---------------- bf16 helpers (RNE) ----------------
__device__ __forceinline__ u16 f2bf(float f) {
    union { float f; unsigned u; } v; v.f = f;
    unsigned u = v.u;
    unsigned r = (u + 0x7FFFu + ((u >> 16) & 1u)) >> 16;
    return (u16)r;
}
__device__ __forceinline__ float bf2f(u16 h) {
    union { unsigned u; float f; } v; v.u = ((unsigned)h) << 16;
    return v.f;
}

// ---------------- utility ----------------
__global__ void k_zero(float* p, int n) {
    int i = blockIdx.x * 256 + threadIdx.x;
    if (i < n) p[i] = 0.f;
}

__global__ void k_deg(const int* __restrict__ src, const int* __restrict__ dst,
                      int* __restrict__ dego, int* __restrict__ degi) {
    int e = blockIdx.x * 256 + threadIdx.x;
    if (e < E_) {
        atomicAdd(&dego[src[e]], 1);
        atomicAdd(&degi[dst[e]], 1);
    }
}

__global__ void k_norm(const int* __restrict__ dego, const int* __restrict__ degi,
                       float* __restrict__ wout, float* __restrict__ win) {
    int n = blockIdx.x * 256 + threadIdx.x;
    if (n < NN) {
        wout[n] = rsqrtf(fmaxf((float)dego[n], 1.f));
        win[n]  = rsqrtf(fmaxf((float)degi[n], 1.f));
    }
}

// exclusive scan of in-degrees -> in_off[0..NN], one block of 512 threads
__global__ void k_scan(const int* __restrict__ degi, int* __restrict__ ioff) {
    __shared__ int part[512];
    int t = threadIdx.x;
    int base = t * 4;
    int v[4]; int s = 0;
#pragma unroll
    for (int i = 0; i < 4; i++) {
        int idx = base + i;
        v[i] = (idx < NN) ? degi[idx] : 0;
        s += v[i];
    }
    part[t] = s;
    __syncthreads();
    for (int o = 1; o < 512; o <<= 1) {
        int x = 0;
        if (t >= o) x = part[t - o];
        __syncthreads();
        part[t] += x;
        __syncthreads();
    }
    int run = (t == 0) ? 0 : part[t - 1];
#pragma unroll
    for (int i = 0; i < 4; i++) {
        int idx = base + i;
        if (idx <= NN) ioff[idx] = run;
        run += v[i];
    }
}

__global__ void k_fill(const int* __restrict__ src, const int* __restrict__ dst,
                       const float* __restrict__ wout, const float* __restrict__ win,
                       const int* __restrict__ ioff, int* __restrict__ cursor,
                       int* __restrict__ csrc, float* __restrict__ csrw) {
    int e = blockIdx.x * 256 + threadIdx.x;
    if (e < E_) {
        int d = dst[e];
        int s = src[e];
        int p = atomicAdd(&cursor[d], 1);
        int i = ioff[d] + p;
        csrc[i] = s;
        csrw[i] = wout[s] * win[d];
    }
}

// transpose W (256x256) into bf16 hi/lo planes: T*[n*256+k] = split(W[k*256+n])
__global__ __launch_bounds__(256) void k_prepw(const float* __restrict__ W,
                                               u16* __restrict__ Th,
                                               u16* __restrict__ Tl) {
    int n = blockIdx.x, k = threadIdx.x;
    float w = W[(size_t)k * 256 + n];
    u16 h = f2bf(w);
    Th[n * 256 + k] = h;
    Tl[n * 256 + k] = f2bf(w - bf2f(h));
}

// scalar graph conv of the input node feature: a[b,n] = sum_e csrw * inp_x[b,src]
__global__ __launch_bounds__(64) void k_agg_scalar(
        const float* __restrict__ inp, const int* __restrict__ ioff,
        const int* __restrict__ csrc, const float* __restrict__ csrw,
        float* __restrict__ a) {
    int n = blockIdx.x * 64 + threadIdx.x;
    int b = blockIdx.y;
    if (n >= NN) return;
    const float* row = inp + (size_t)b * ROWST + CIN;
    int e0 = ioff[n], e1 = ioff[n + 1];
    float acc = 0.f;
    for (int i = e0; i < e1; i++) acc += csrw[i] * row[csrc[i]];
    a[(size_t)b * NN + n] = acc;
}

// layer-0 pooling straight from a: x0[b,n,c] = relu(a*W0[c]+b0[c])
__global__ __launch_bounds__(256) void k_pool0(
        const float* __restrict__ a, const float* __restrict__ W0,
        const float* __restrict__ b0, float* __restrict__ hg) {
    int b = blockIdx.x, c = threadIdx.x;
    float w0c = W0[c], b0c = b0[c];
    const float* ab = a + (size_t)b * NN;
    float s = 0.f, mx = 0.f;
    for (int n = 0; n < NN; n++) {
        float v = fmaxf(fmaf(ab[n], w0c, b0c), 0.f);
        s += v;
        mx = fmaxf(mx, v);
    }
    hg[(size_t)b * 512 + c]       += s * (1.f / (float)NN);
    hg[(size_t)b * 512 + 256 + c] += mx;
}

// fused layer-0-expand + layer-1 aggregation, bf16 out.
// wave serves 2 batch elems: lanes 0-31 -> bl=2*bp, lanes 32-63 -> 2*bp+1.
__global__ __launch_bounds__(64) void k_agg_l1(
        const float* __restrict__ a, const int* __restrict__ ioff,
        const int* __restrict__ csrc, const float* __restrict__ csrw,
        const float* __restrict__ W0, const float* __restrict__ b0,
        u16* __restrict__ xout, int b0g) {
    int n = blockIdx.x, bp = blockIdx.y, t = threadIdx.x;
    int half = t >> 5, c8 = (t & 31) * 8;
    int bl = bp * 2 + half;
    int e0 = ioff[n], e1 = ioff[n + 1];
    const float* ab = a + (size_t)(b0g + bl) * NN;
    float w[8], bb[8], acc[8];
#pragma unroll
    for (int j = 0; j < 8; j++) { w[j] = W0[c8 + j]; bb[j] = b0[c8 + j]; acc[j] = 0.f; }
    for (int i = e0; i < e1; i++) {
        float av = ab[csrc[i]];
        float we = csrw[i];
#pragma unroll
        for (int j = 0; j < 8; j++)
            acc[j] = fmaf(fmaxf(fmaf(av, w[j], bb[j]), 0.f), we, acc[j]);
    }
    ush8 o;
#pragma unroll
    for (int j = 0; j < 8; j++) o[j] = f2bf(acc[j]);
    *reinterpret_cast<ush8*>(&xout[((size_t)bl * NN + n) * C_ + c8]) = o;
}

// layer-2 aggregation, bf16 in/out, 2 bl per wave, 16B/lane gathers.
// XCD-locality swizzle (verified round 3).
__global__ __launch_bounds__(64) void k_agg_bf(
        const u16* __restrict__ xin, const int* __restrict__ ioff,
        const int* __restrict__ csrc, const float* __restrict__ csrw,
        u16* __restrict__ xout, int QBH) {
    int l = blockIdx.x + NN * blockIdx.y;   // HW linear workgroup id (x fastest)
    int xcd = l & 7, slot = l >> 3;
    int q = slot / NN;
    int bp = xcd * QBH + q;
    int n = slot - q * NN;
    int t = threadIdx.x;
    int half = t >> 5, c8 = (t & 31) * 8;
    int bl = bp * 2 + half;
    int e0 = ioff[n], e1 = ioff[n + 1];
    const u16* xb = xin + (size_t)bl * NN * C_ + c8;
    float acc[8] = {};
    for (int i = e0; i < e1; i++) {
        int s = csrc[i];
        float wgt = csrw[i];
        ush8 v = *reinterpret_cast<const ush8*>(&xb[(size_t)s * C_]);
#pragma unroll
        for (int j = 0; j < 8; j++) acc[j] = fmaf(bf2f(v[j]), wgt, acc[j]);
    }
    ush8 o;
#pragma unroll
    for (int j = 0; j < 8; j++) o[j] = f2bf(acc[j]);
    *reinterpret_cast<ush8*>(&xout[((size_t)bl * NN + n) * C_ + c8]) = o;
}

// ---------------- MFMA GEMM (bf16 A) with fused pooling ----------------
// C = relu(A @ W + bias); pool (sum,max) per (bl, col) into psum/pmax atomics.
// A bf16 (one rounding), W hi/lo bf16 -> 2 MFMA passes.
// OUT: 0 = pool only (no C write), 1 = write C as bf16.
#define GM 128
#define GN 128
#define GK 32
#define LDP 40   // padded u16 row stride (80 B)

template<int OUT>
__global__ __launch_bounds__(256) void k_gemm_mfma(
        const u16* __restrict__ Abf, const u16* __restrict__ WTh,
        const u16* __restrict__ WTl, const float* __restrict__ bias,
        u16* __restrict__ Cbf, float* __restrict__ psum, float* __restrict__ pmax) {
    __shared__ u16 Ah[GM * LDP];
    __shared__ u16 Bh[GN * LDP];
    __shared__ u16 Bl[GN * LDP];
    __shared__ float lsum[2][2][GN];
    __shared__ float lmax[2][2][GN];
    int tid  = threadIdx.x;
    int lane = tid & 63, wave = tid >> 6;
    int wm = wave >> 1, wn = wave & 1;
    int n0 = blockIdx.x * GN;
    int m0 = blockIdx.y * GM;
    int blk = lane >> 4, rr = lane & 15;

    f32x4 acc[4][4] = {};

    for (int k0 = 0; k0 < 256; k0 += GK) {
        // stage A: 128 rows x 32 k bf16 (512 x 16B segs, 2/thread)
#pragma unroll
        for (int q = 0; q < 2; q++) {
            int f = tid + 256 * q;
            int row = f >> 2, seg = f & 3;
            ush8 v = *reinterpret_cast<const ush8*>(
                &Abf[(size_t)(m0 + row) * 256 + k0 + seg * 8]);
            *reinterpret_cast<ush8*>(&Ah[row * LDP + seg * 8]) = v;
        }
        // stage B hi/lo: 128 n-rows x 32 k each
#pragma unroll
        for (int q = 0; q < 2; q++) {
            int f = tid + 256 * q;
            int row = f >> 2, seg = f & 3;
            ush8 vh = *reinterpret_cast<const ush8*>(
                &WTh[(size_t)(n0 + row) * 256 + k0 + seg * 8]);
            ush8 vl = *reinterpret_cast<const ush8*>(
                &WTl[(size_t)(n0 + row) * 256 + k0 + seg * 8]);
            *reinterpret_cast<ush8*>(&Bh[row * LDP + seg * 8]) = vh;
            *reinterpret_cast<ush8*>(&Bl[row * LDP + seg * 8]) = vl;
        }
        __syncthreads();

        short8 af[4], bh[4], bl_[4];
#pragma unroll
        for (int mr = 0; mr < 4; mr++)
            af[mr] = *reinterpret_cast<const short8*>(
                &Ah[(wm * 64 + mr * 16 + rr) * LDP + blk * 8]);
#pragma unroll
        for (int nr = 0; nr < 4; nr++) {
            bh[nr]  = *reinterpret_cast<const short8*>(
                &Bh[(wn * 64 + nr * 16 + rr) * LDP + blk * 8]);
            bl_[nr] = *reinterpret_cast<const short8*>(
                &Bl[(wn * 64 + nr * 16 + rr) * LDP + blk * 8]);
        }
#pragma unroll
        for (int mr = 0; mr < 4; mr++)
#pragma unroll
            for (int nr = 0; nr < 4; nr++) {
                acc[mr][nr] = __builtin_amdgcn_mfma_f32_16x16x32_bf16(
                    af[mr], bh[nr], acc[mr][nr], 0, 0, 0);
                acc[mr][nr] = __builtin_amdgcn_mfma_f32_16x16x32_bf16(
                    af[mr], bl_[nr], acc[mr][nr], 0, 0, 0);
            }
        __syncthreads();
    }

    // epilogue: bias + relu, optional bf16 store, fused (sum,max) pool
    int bl0   = m0 / NN;
    int split = (bl0 + 1) * NN - m0;   // local rows >= split belong to bl0+1

    float s_lo[4] = {}, s_hi[4] = {}, m_lo[4] = {}, m_hi[4] = {};
#pragma unroll
    for (int nr = 0; nr < 4; nr++) {
        int col = n0 + wn * 64 + nr * 16 + rr;
        float bs = bias[col];
#pragma unroll
        for (int mr = 0; mr < 4; mr++) {
            int rl = wm * 64 + mr * 16 + blk * 4;
#pragma unroll
            for (int j = 0; j < 4; j++) {
                float v = fmaxf(acc[mr][nr][j] + bs, 0.f);
                if (OUT == 1)
                    Cbf[(size_t)(m0 + rl + j) * 256 + col] = f2bf(v);
                bool second = (rl + j) >= split;
                s_lo[nr] += second ? 0.f : v;
                s_hi[nr] += second ? v : 0.f;
                m_lo[nr] = second ? m_lo[nr] : fmaxf(m_lo[nr], v);
                m_hi[nr] = second ? fmaxf(m_hi[nr], v) : m_hi[nr];
            }
        }
    }
#pragma unroll
    for (int nr = 0; nr < 4; nr++) {
        s_lo[nr] += __shfl_xor(s_lo[nr], 16); s_lo[nr] += __shfl_xor(s_lo[nr], 32);
        s_hi[nr] += __shfl_xor(s_hi[nr], 16); s_hi[nr] += __shfl_xor(s_hi[nr], 32);
        m_lo[nr] = fmaxf(m_lo[nr], __shfl_xor(m_lo[nr], 16));
        m_lo[nr] = fmaxf(m_lo[nr], __shfl_xor(m_lo[nr], 32));
        m_hi[nr] = fmaxf(m_hi[nr], __shfl_xor(m_hi[nr], 16));
        m_hi[nr] = fmaxf(m_hi[nr], __shfl_xor(m_hi[nr], 32));
    }
    if (lane < 16) {
#pragma unroll
        for (int nr = 0; nr < 4; nr++) {
            int cl = wn * 64 + nr * 16 + lane;
            lsum[0][wm][cl] = s_lo[nr];
            lsum[1][wm][cl] = s_hi[nr];
            lmax[0][wm][cl] = m_lo[nr];
            lmax[1][wm][cl] = m_hi[nr];
        }
    }
    __syncthreads();
    {
        int seg = tid >> 7, cl = tid & 127;
        if (!(seg == 1 && split >= GM)) {
            float s = lsum[seg][0][cl] + lsum[seg][1][cl];
            float m = fmaxf(lmax[seg][0][cl], lmax[seg][1][cl]);
            int blx = bl0 + seg;
            atomicAdd(&psum[blx * C_ + n0 + cl], s);
            atomicMax((unsigned int*)&pmax[blx * C_ + n0 + cl], __float_as_uint(m));
        }
    }
}

// combine fused-pool results into hg, then reset psum/pmax for next use
__global__ __launch_bounds__(256) void k_pool_combine(
        float* __restrict__ psum, float* __restrict__ pmax,
        float* __restrict__ hg, int b0g) {
    int bl = blockIdx.x, c = threadIdx.x;
    float s = psum[bl * C_ + c];
    float m = pmax[bl * C_ + c];
    psum[bl * C_ + c] = 0.f;
    pmax[bl * C_ + c] = 0.f;
    size_t b = b0g + bl;
    hg[b * 512 + c]       += s * (1.f / (float)NN);
    hg[b * 512 + 256 + c] += m;
}

__global__ __launch_bounds__(128) void k_embed(
        const float* __restrict__ inp, const float* __restrict__ We,
        float* __restrict__ emb) {
    int b = blockIdx.x, c = threadIdx.x;
    const float* row = inp + (size_t)b * ROWST;
    float a = 0.f;
    for (int k = 0; k < CIN; k++) a += row[k] * We[k * CEMB + c];
    emb[b * CEMB + c] = fmaxf(a, 0.f);
}

__global__ __launch_bounds__(512) void k_mlp1(
        const float* __restrict__ emb, const float* __restrict__ hg,
        const float* __restrict__ Wh1, const float* __restrict__ bh1,
        float* __restrict__ h1) {
    __shared__ float fus[FUSD];
    int b = blockIdx.x, j = threadIdx.x;
    if (j < CEMB) fus[j] = emb[b * CEMB + j];
    fus[CEMB + j] = hg[(size_t)b * 512 + j];
    __syncthreads();
    float a = bh1[j];
    for (int k = 0; k < FUSD; k++) a += fus[k] * Wh1[(size_t)k * HAZ1 + j];
    h1[(size_t)b * HAZ1 + j] = fmaxf(a, 0.f);
}

__global__ __launch_bounds__(256) void k_mlp2(
        const float* __restrict__ h1, const float* __restrict__ Wh2,
        const float* __restrict__ bh2, float* __restrict__ h2) {
    __shared__ float f2[HAZ1];
    int b = blockIdx.x, j = threadIdx.x;
    f2[j]       = h1[(size_t)b * HAZ1 + j];
    f2[256 + j] = h1[(size_t)b * HAZ1 + 256 + j];
    __syncthreads();
    float a = bh2[j];
    for (int k = 0; k < HAZ1; k++) a += f2[k] * Wh2[(size_t)k * HAZ2 + j];
    h2[(size_t)b * HAZ2 + j] = fmaxf(a, 0.f);
}

__global__ __launch_bounds__(256) void k_out(
        const float* __restrict__ h2, const float* __restrict__ Wh3,
        float* __restrict__ out) {
    __shared__ float red[256];
    int b = blockIdx.x, t = threadIdx.x;
    red[t] = h2[(size_t)b * HAZ2 + t] * Wh3[t];
    __syncthreads();
    for (int o = 128; o > 0; o >>= 1) {
        if (t < o) red[t] += red[t + o];
        __syncthreads();
    }
    if (t == 0) out[b] = red[0];
}

// ---------------- launch ----------------
extern "C" void kernel_launch(void* const* d_in, const int* in_sizes, int n_in,
                              void* d_out, int out_size, void* d_ws, size_t ws_size,
                              hipStream_t stream) {
    const float* inp = (const float*)d_in[0];
    const int*   src = (const int*)d_in[1];
    const int*   dst = (const int*)d_in[2];
    const float* W0  = (const float*)d_in[3];
    const float* b0  = (const float*)d_in[4];
    const float* W1  = (const float*)d_in[5];
    const float* b1  = (const float*)d_in[6];
    const float* W2  = (const float*)d_in[7];
    const float* b2  = (const float*)d_in[8];
    const float* We  = (const float*)d_in[9];
    const float* Wh1 = (const float*)d_in[10];
    const float* bh1 = (const float*)d_in[11];
    const float* Wh2 = (const float*)d_in[12];
    const float* bh2 = (const float*)d_in[13];
    const float* Wh3 = (const float*)d_in[14];
    float* out = (float*)d_out;

    char* ws = (char*)d_ws;
    int*   dego = (int*)(ws + OFF_DEGO);
    int*   degi = (int*)(ws + OFF_DEGI);
    int*   cur  = (int*)(ws + OFF_CUR);
    float* wout = (float*)(ws + OFF_WOUT);
    float* win  = (float*)(ws + OFF_WIN);
    int*   ioff = (int*)(ws + OFF_IOFF);
    int*   csrc = (int*)(ws + OFF_CSRC);
    float* csrw = (float*)(ws + OFF_CSRW);
    float* hg   = (float*)(ws + OFF_HG);
    float* emb  = (float*)(ws + OFF_EMB);
    float* h1   = (float*)(ws + OFF_H1);
    float* h2   = (float*)(ws + OFF_H2);
    float* psum = (float*)(ws + OFF_PSUM);
    float* pmax = (float*)(ws + OFF_PMAX);
    float* avec = (float*)(ws + OFF_A);
    u16*   wt1h = (u16*)(ws + OFF_WT1H);
    u16*   wt1l = (u16*)(ws + OFF_WT1L);
    u16*   wt2h = (u16*)(ws + OFF_WT2H);
    u16*   wt2l = (u16*)(ws + OFF_WT2L);

    // ---- choose batch-chunk size CB ----
    // need = OFF_XBUF + CB * 2 * (NN*C_*2)  (two bf16 x buffers)
    // CB multiple of 16 (CBH%8==0 for the agg swizzle; CB*NN%GM==0).
    const size_t perb = (size_t)NN * C_ * 4;
    int CB = 128;
    while (CB > 16 && OFF_XBUF + (size_t)CB * perb > ws_size) CB >>= 1;
    int nchunk = B_ / CB;
    int CBH = CB / 2;
    int QBH = CBH / 8;

    u16* xB   = (u16*)(ws + OFF_XBUF);                              // agg out (GEMM A)
    u16* xAbf = (u16*)(ws + OFF_XBUF + (size_t)CB * NN * C_ * 2);   // bf16 x1

    // zeros: deg counters (6000 ints), hg, psum+pmax (contiguous 65536 floats)
    k_zero<<<dim3((6000 + 255) / 256), 256, 0, stream>>>((float*)dego, 6000);
    k_zero<<<dim3((65536 + 255) / 256), 256, 0, stream>>>(hg, 65536);
    k_zero<<<dim3((65536 + 255) / 256), 256, 0, stream>>>(psum, 65536);

    // graph normalization + CSR build + weight transpose/split
    k_deg<<<dim3((E_ + 255) / 256), 256, 0, stream>>>(src, dst, dego, degi);
    k_norm<<<dim3((NN + 255) / 256), 256, 0, stream>>>(dego, degi, wout, win);
    k_scan<<<1, 512, 0, stream>>>(degi, ioff);
    k_fill<<<dim3((E_ + 255) / 256), 256, 0, stream>>>(src, dst, wout, win, ioff, cur, csrc, csrw);
    k_prepw<<<256, 256, 0, stream>>>(W1, wt1h, wt1l);
    k_prepw<<<256, 256, 0, stream>>>(W2, wt2h, wt2l);

    // scalar conv of input feature (all B), layer-0 pooling from it
    k_agg_scalar<<<dim3((NN + 63) / 64, B_), 64, 0, stream>>>(inp, ioff, csrc, csrw, avec);
    k_pool0<<<B_, 256, 0, stream>>>(avec, W0, b0, hg);

    dim3 gridNB(NN, CBH);
    dim3 gridGemm(C_ / GN, (CB * NN) / GM);

    for (int c = 0; c < nchunk; ++c) {
        int b0g = c * CB;

        // layer 1: fused expand+agg -> xB (bf16); MFMA gemm + fused pool -> xA (bf16)
        k_agg_l1<<<gridNB, 64, 0, stream>>>(avec, ioff, csrc, csrw, W0, b0, xB, b0g);
        k_gemm_mfma<1><<<gridGemm, 256, 0, stream>>>(xB, wt1h, wt1l, b1, xAbf, psum, pmax);
        k_pool_combine<<<CB, 256, 0, stream>>>(psum, pmax, hg, b0g);

        // layer 2: bf16 gather agg -> xB; MFMA gemm, pool only (no C write)
        k_agg_bf<<<gridNB, 64, 0, stream>>>(xAbf, ioff, csrc, csrw, xB, QBH);
        k_gemm_mfma<0><<<gridGemm, 256, 0, stream>>>(xB, wt2h, wt2l, b2, nullptr, psum, pmax);
        k_pool_combine<<<CB, 256, 0, stream>>>(psum, pmax, hg, b0g);
    }

    // head
    k_embed<<<B_, 128, 0, stream>>>(inp, We, emb);
    k_mlp1<<<B_, 512, 0, stream>>>(emb, hg, Wh1, bh1, h1);
    k_mlp2<<<B_, 256, 0, stream>>>(h1, Wh2, bh2, h2);
    k_out<<<B_, 256, 0, stream>>>(h2, Wh3, out);
}

// Round 6
// 642.323 us; speedup vs baseline: 4.2719x; 1.1368x over previous
//
#include <hip/hip_runtime.h>
#include <hip/hip_bf16.h>

// ---------------- problem constants ----------------
#define B_    128
#define NN    2000
#define C_    256
#define E_    64000
#define CIN   64
#define ROWST 2064   // CIN + NN
#define CEMB  128
#define HAZ1  512
#define HAZ2  256
#define FUSD  640    // CEMB + 2*C_

typedef unsigned short u16;
typedef __attribute__((ext_vector_type(8))) short short8;
typedef __attribute__((ext_vector_type(8))) unsigned short ush8;
typedef __attribute__((ext_vector_type(4))) float f32x4;

// ---------------- workspace layout (bytes) ----------------
static constexpr size_t OFF_DEGO = 0;        // int[2000]
static constexpr size_t OFF_DEGI = 8000;     // int[2000]
static constexpr size_t OFF_CUR  = 16000;    // int[2000]
static constexpr size_t OFF_WOUT = 24000;    // float[2000]
static constexpr size_t OFF_WIN  = 32000;    // float[2000]
static constexpr size_t OFF_IOFF = 40000;    // int[2001] (padded)
static constexpr size_t OFF_CSRC = 48192;    // int[64000]
static constexpr size_t OFF_CSRW = 304192;   // float[64000]
static constexpr size_t OFF_HG   = 560192;   // float[128*512]           -> 822336
static constexpr size_t OFF_EMB  = 822336;   // float[128*128]           -> 887872
static constexpr size_t OFF_H1   = 887872;   // float[128*512]           -> 1150016
static constexpr size_t OFF_H2   = 1150016;  // float[128*256]           -> 1281088
static constexpr size_t OFF_PSUM = 1281088;  // float[128*256]           -> 1412160
static constexpr size_t OFF_PMAX = 1412160;  // float[128*256]           -> 1543232
static constexpr size_t OFF_A    = 1543232;  // float[128*2000]          -> 2567232
static constexpr size_t OFF_WT1H = 2567232;  // u16[256*256]             -> 2698304
static constexpr size_t OFF_WT2H = 2829376;  //                          -> 2960448
static constexpr size_t OFF_XBUF = 4194304;  // xB bf16 [CB*NN*C_], then xA bf16 [CB*NN*C_]

// ---------------- bf16 helpers (RNE) ----------------
__device__ __forceinline__ u16 f2bf(float f) {
    union { float f; unsigned u; } v; v.f = f;
    unsigned u = v.u;
    unsigned r = (u + 0x7FFFu + ((u >> 16) & 1u)) >> 16;
    return (u16)r;
}
__device__ __forceinline__ float bf2f(u16 h) {
    union { unsigned u; float f; } v; v.u = ((unsigned)h) << 16;
    return v.f;
}

// ---------------- utility ----------------
__global__ void k_zero(float* p, int n) {
    int i = blockIdx.x * 256 + threadIdx.x;
    if (i < n) p[i] = 0.f;
}

__global__ void k_deg(const int* __restrict__ src, const int* __restrict__ dst,
                      int* __restrict__ dego, int* __restrict__ degi) {
    int e = blockIdx.x * 256 + threadIdx.x;
    if (e < E_) {
        atomicAdd(&dego[src[e]], 1);
        atomicAdd(&degi[dst[e]], 1);
    }
}

__global__ void k_norm(const int* __restrict__ dego, const int* __restrict__ degi,
                       float* __restrict__ wout, float* __restrict__ win) {
    int n = blockIdx.x * 256 + threadIdx.x;
    if (n < NN) {
        wout[n] = rsqrtf(fmaxf((float)dego[n], 1.f));
        win[n]  = rsqrtf(fmaxf((float)degi[n], 1.f));
    }
}

// exclusive scan of in-degrees -> in_off[0..NN], one block of 512 threads
__global__ void k_scan(const int* __restrict__ degi, int* __restrict__ ioff) {
    __shared__ int part[512];
    int t = threadIdx.x;
    int base = t * 4;
    int v[4]; int s = 0;
#pragma unroll
    for (int i = 0; i < 4; i++) {
        int idx = base + i;
        v[i] = (idx < NN) ? degi[idx] : 0;
        s += v[i];
    }
    part[t] = s;
    __syncthreads();
    for (int o = 1; o < 512; o <<= 1) {
        int x = 0;
        if (t >= o) x = part[t - o];
        __syncthreads();
        part[t] += x;
        __syncthreads();
    }
    int run = (t == 0) ? 0 : part[t - 1];
#pragma unroll
    for (int i = 0; i < 4; i++) {
        int idx = base + i;
        if (idx <= NN) ioff[idx] = run;
        run += v[i];
    }
}

__global__ void k_fill(const int* __restrict__ src, const int* __restrict__ dst,
                       const float* __restrict__ wout, const float* __restrict__ win,
                       const int* __restrict__ ioff, int* __restrict__ cursor,
                       int* __restrict__ csrc, float* __restrict__ csrw) {
    int e = blockIdx.x * 256 + threadIdx.x;
    if (e < E_) {
        int d = dst[e];
        int s = src[e];
        int p = atomicAdd(&cursor[d], 1);
        int i = ioff[d] + p;
        csrc[i] = s;
        csrw[i] = wout[s] * win[d];
    }
}

// transpose W (256x256) into bf16: T[n*256+k] = bf16(W[k*256+n])
__global__ __launch_bounds__(256) void k_prepw(const float* __restrict__ W,
                                               u16* __restrict__ Th) {
    int n = blockIdx.x, k = threadIdx.x;
    Th[n * 256 + k] = f2bf(W[(size_t)k * 256 + n]);
}

// scalar graph conv of the input node feature: a[b,n] = sum_e csrw * inp_x[b,src]
__global__ __launch_bounds__(64) void k_agg_scalar(
        const float* __restrict__ inp, const int* __restrict__ ioff,
        const int* __restrict__ csrc, const float* __restrict__ csrw,
        float* __restrict__ a) {
    int n = blockIdx.x * 64 + threadIdx.x;
    int b = blockIdx.y;
    if (n >= NN) return;
    const float* row = inp + (size_t)b * ROWST + CIN;
    int e0 = ioff[n], e1 = ioff[n + 1];
    float acc = 0.f;
    for (int i = e0; i < e1; i++) acc += csrw[i] * row[csrc[i]];
    a[(size_t)b * NN + n] = acc;
}

// layer-0 pooling straight from a: x0[b,n,c] = relu(a*W0[c]+b0[c])
__global__ __launch_bounds__(256) void k_pool0(
        const float* __restrict__ a, const float* __restrict__ W0,
        const float* __restrict__ b0, float* __restrict__ hg) {
    int b = blockIdx.x, c = threadIdx.x;
    float w0c = W0[c], b0c = b0[c];
    const float* ab = a + (size_t)b * NN;
    float s = 0.f, mx = 0.f;
    for (int n = 0; n < NN; n++) {
        float v = fmaxf(fmaf(ab[n], w0c, b0c), 0.f);
        s += v;
        mx = fmaxf(mx, v);
    }
    hg[(size_t)b * 512 + c]       += s * (1.f / (float)NN);
    hg[(size_t)b * 512 + 256 + c] += mx;
}

// fused layer-0-expand + layer-1 aggregation, bf16 out, edge-loop unroll x2.
// wave serves 2 batch elems: lanes 0-31 -> bl=2*bp, lanes 32-63 -> 2*bp+1.
__global__ __launch_bounds__(64) void k_agg_l1(
        const float* __restrict__ a, const int* __restrict__ ioff,
        const int* __restrict__ csrc, const float* __restrict__ csrw,
        const float* __restrict__ W0, const float* __restrict__ b0,
        u16* __restrict__ xout, int b0g) {
    int n = blockIdx.x, bp = blockIdx.y, t = threadIdx.x;
    int half = t >> 5, c8 = (t & 31) * 8;
    int bl = bp * 2 + half;
    int e0 = ioff[n], e1 = ioff[n + 1];
    const float* ab = a + (size_t)(b0g + bl) * NN;
    float w[8], bb[8], acca[8] = {}, accb[8] = {};
#pragma unroll
    for (int j = 0; j < 8; j++) { w[j] = W0[c8 + j]; bb[j] = b0[c8 + j]; }
    int i = e0;
    for (; i + 2 <= e1; i += 2) {
        float a0 = ab[csrc[i]],     we0 = csrw[i];
        float a1 = ab[csrc[i + 1]], we1 = csrw[i + 1];
#pragma unroll
        for (int j = 0; j < 8; j++) {
            acca[j] = fmaf(fmaxf(fmaf(a0, w[j], bb[j]), 0.f), we0, acca[j]);
            accb[j] = fmaf(fmaxf(fmaf(a1, w[j], bb[j]), 0.f), we1, accb[j]);
        }
    }
    if (i < e1) {
        float a0 = ab[csrc[i]], we0 = csrw[i];
#pragma unroll
        for (int j = 0; j < 8; j++)
            acca[j] = fmaf(fmaxf(fmaf(a0, w[j], bb[j]), 0.f), we0, acca[j]);
    }
    ush8 o;
#pragma unroll
    for (int j = 0; j < 8; j++) o[j] = f2bf(acca[j] + accb[j]);
    *reinterpret_cast<ush8*>(&xout[((size_t)bl * NN + n) * C_ + c8]) = o;
}

// layer-2 aggregation, bf16 in/out, 2 bl per wave, 16B/lane gathers, unroll x2.
// XCD-locality swizzle (verified round 3: over-fetch eliminated).
__global__ __launch_bounds__(64) void k_agg_bf(
        const u16* __restrict__ xin, const int* __restrict__ ioff,
        const int* __restrict__ csrc, const float* __restrict__ csrw,
        u16* __restrict__ xout, int QBH) {
    int l = blockIdx.x + NN * blockIdx.y;   // HW linear workgroup id (x fastest)
    int xcd = l & 7, slot = l >> 3;
    int q = slot / NN;
    int bp = xcd * QBH + q;
    int n = slot - q * NN;
    int t = threadIdx.x;
    int half = t >> 5, c8 = (t & 31) * 8;
    int bl = bp * 2 + half;
    int e0 = ioff[n], e1 = ioff[n + 1];
    const u16* xb = xin + (size_t)bl * NN * C_ + c8;
    float acca[8] = {}, accb[8] = {};
    int i = e0;
    for (; i + 2 <= e1; i += 2) {
        int s0 = csrc[i];     float w0 = csrw[i];
        int s1 = csrc[i + 1]; float w1 = csrw[i + 1];
        ush8 v0 = *reinterpret_cast<const ush8*>(&xb[(size_t)s0 * C_]);
        ush8 v1 = *reinterpret_cast<const ush8*>(&xb[(size_t)s1 * C_]);
#pragma unroll
        for (int j = 0; j < 8; j++) {
            acca[j] = fmaf(bf2f(v0[j]), w0, acca[j]);
            accb[j] = fmaf(bf2f(v1[j]), w1, accb[j]);
        }
    }
    if (i < e1) {
        int s0 = csrc[i]; float w0 = csrw[i];
        ush8 v0 = *reinterpret_cast<const ush8*>(&xb[(size_t)s0 * C_]);
#pragma unroll
        for (int j = 0; j < 8; j++) acca[j] = fmaf(bf2f(v0[j]), w0, acca[j]);
    }
    ush8 o;
#pragma unroll
    for (int j = 0; j < 8; j++) o[j] = f2bf(acca[j] + accb[j]);
    *reinterpret_cast<ush8*>(&xout[((size_t)bl * NN + n) * C_ + c8]) = o;
}

// ---------------- MFMA GEMM (bf16 A, bf16 W, 1 pass) with fused pooling ----
// C = relu(A @ W + bias); pool (sum,max) per (bl, col) into psum/pmax atomics.
// OUT: 0 = pool only (no C write), 1 = write C as bf16.
#define GM 128
#define GN 128
#define GK 32
#define LDP 40   // padded u16 row stride (80 B) -> 2-way banks max on ds_read_b128

template<int OUT>
__global__ __launch_bounds__(256) void k_gemm_mfma(
        const u16* __restrict__ Abf, const u16* __restrict__ WTh,
        const float* __restrict__ bias,
        u16* __restrict__ Cbf, float* __restrict__ psum, float* __restrict__ pmax) {
    __shared__ u16 Ah[GM * LDP];
    __shared__ u16 Bh[GN * LDP];
    __shared__ float lsum[2][2][GN];
    __shared__ float lmax[2][2][GN];
    int tid  = threadIdx.x;
    int lane = tid & 63, wave = tid >> 6;
    int wm = wave >> 1, wn = wave & 1;
    int n0 = blockIdx.x * GN;
    int m0 = blockIdx.y * GM;
    int blk = lane >> 4, rr = lane & 15;

    f32x4 acc[4][4] = {};

    for (int k0 = 0; k0 < 256; k0 += GK) {
        // stage A + B: each 128 rows x 32 k bf16 = 512 x 16B segs, 2/thread
#pragma unroll
        for (int q = 0; q < 2; q++) {
            int f = tid + 256 * q;
            int row = f >> 2, seg = f & 3;
            ush8 va = *reinterpret_cast<const ush8*>(
                &Abf[(size_t)(m0 + row) * 256 + k0 + seg * 8]);
            ush8 vb = *reinterpret_cast<const ush8*>(
                &WTh[(size_t)(n0 + row) * 256 + k0 + seg * 8]);
            *reinterpret_cast<ush8*>(&Ah[row * LDP + seg * 8]) = va;
            *reinterpret_cast<ush8*>(&Bh[row * LDP + seg * 8]) = vb;
        }
        __syncthreads();

        short8 af[4], bf[4];
#pragma unroll
        for (int mr = 0; mr < 4; mr++)
            af[mr] = *reinterpret_cast<const short8*>(
                &Ah[(wm * 64 + mr * 16 + rr) * LDP + blk * 8]);
#pragma unroll
        for (int nr = 0; nr < 4; nr++)
            bf[nr] = *reinterpret_cast<const short8*>(
                &Bh[(wn * 64 + nr * 16 + rr) * LDP + blk * 8]);
#pragma unroll
        for (int mr = 0; mr < 4; mr++)
#pragma unroll
            for (int nr = 0; nr < 4; nr++)
                acc[mr][nr] = __builtin_amdgcn_mfma_f32_16x16x32_bf16(
                    af[mr], bf[nr], acc[mr][nr], 0, 0, 0);
        __syncthreads();
    }

    // epilogue: bias + relu, optional bf16 store, fused (sum,max) pool
    int bl0   = m0 / NN;
    int split = (bl0 + 1) * NN - m0;   // local rows >= split belong to bl0+1

    float s_lo[4] = {}, s_hi[4] = {}, m_lo[4] = {}, m_hi[4] = {};
#pragma unroll
    for (int nr = 0; nr < 4; nr++) {
        int col = n0 + wn * 64 + nr * 16 + rr;
        float bs = bias[col];
#pragma unroll
        for (int mr = 0; mr < 4; mr++) {
            int rl = wm * 64 + mr * 16 + blk * 4;
#pragma unroll
            for (int j = 0; j < 4; j++) {
                float v = fmaxf(acc[mr][nr][j] + bs, 0.f);
                if (OUT == 1)
                    Cbf[(size_t)(m0 + rl + j) * 256 + col] = f2bf(v);
                bool second = (rl + j) >= split;
                s_lo[nr] += second ? 0.f : v;
                s_hi[nr] += second ? v : 0.f;
                m_lo[nr] = second ? m_lo[nr] : fmaxf(m_lo[nr], v);
                m_hi[nr] = second ? fmaxf(m_hi[nr], v) : m_hi[nr];
            }
        }
    }
#pragma unroll
    for (int nr = 0; nr < 4; nr++) {
        s_lo[nr] += __shfl_xor(s_lo[nr], 16); s_lo[nr] += __shfl_xor(s_lo[nr], 32);
        s_hi[nr] += __shfl_xor(s_hi[nr], 16); s_hi[nr] += __shfl_xor(s_hi[nr], 32);
        m_lo[nr] = fmaxf(m_lo[nr], __shfl_xor(m_lo[nr], 16));
        m_lo[nr] = fmaxf(m_lo[nr], __shfl_xor(m_lo[nr], 32));
        m_hi[nr] = fmaxf(m_hi[nr], __shfl_xor(m_hi[nr], 16));
        m_hi[nr] = fmaxf(m_hi[nr], __shfl_xor(m_hi[nr], 32));
    }
    if (lane < 16) {
#pragma unroll
        for (int nr = 0; nr < 4; nr++) {
            int cl = wn * 64 + nr * 16 + lane;
            lsum[0][wm][cl] = s_lo[nr];
            lsum[1][wm][cl] = s_hi[nr];
            lmax[0][wm][cl] = m_lo[nr];
            lmax[1][wm][cl] = m_hi[nr];
        }
    }
    __syncthreads();
    {
        int seg = tid >> 7, cl = tid & 127;
        if (!(seg == 1 && split >= GM)) {
            float s = lsum[seg][0][cl] + lsum[seg][1][cl];
            float m = fmaxf(lmax[seg][0][cl], lmax[seg][1][cl]);
            int blx = bl0 + seg;
            atomicAdd(&psum[blx * C_ + n0 + cl], s);
            atomicMax((unsigned int*)&pmax[blx * C_ + n0 + cl], __float_as_uint(m));
        }
    }
}

// combine fused-pool results into hg, then reset psum/pmax for next use
__global__ __launch_bounds__(256) void k_pool_combine(
        float* __restrict__ psum, float* __restrict__ pmax,
        float* __restrict__ hg, int b0g) {
    int bl = blockIdx.x, c = threadIdx.x;
    float s = psum[bl * C_ + c];
    float m = pmax[bl * C_ + c];
    psum[bl * C_ + c] = 0.f;
    pmax[bl * C_ + c] = 0.f;
    size_t b = b0g + bl;
    hg[b * 512 + c]       += s * (1.f / (float)NN);
    hg[b * 512 + 256 + c] += m;
}

__global__ __launch_bounds__(128) void k_embed(
        const float* __restrict__ inp, const float* __restrict__ We,
        float* __restrict__ emb) {
    int b = blockIdx.x, c = threadIdx.x;
    const float* row = inp + (size_t)b * ROWST;
    float a = 0.f;
    for (int k = 0; k < CIN; k++) a += row[k] * We[k * CEMB + c];
    emb[b * CEMB + c] = fmaxf(a, 0.f);
}

__global__ __launch_bounds__(512) void k_mlp1(
        const float* __restrict__ emb, const float* __restrict__ hg,
        const float* __restrict__ Wh1, const float* __restrict__ bh1,
        float* __restrict__ h1) {
    __shared__ float fus[FUSD];
    int b = blockIdx.x, j = threadIdx.x;
    if (j < CEMB) fus[j] = emb[b * CEMB + j];
    fus[CEMB + j] = hg[(size_t)b * 512 + j];
    __syncthreads();
    float a = bh1[j];
    for (int k = 0; k < FUSD; k++) a += fus[k] * Wh1[(size_t)k * HAZ1 + j];
    h1[(size_t)b * HAZ1 + j] = fmaxf(a, 0.f);
}

__global__ __launch_bounds__(256) void k_mlp2(
        const float* __restrict__ h1, const float* __restrict__ Wh2,
        const float* __restrict__ bh2, float* __restrict__ h2) {
    __shared__ float f2[HAZ1];
    int b = blockIdx.x, j = threadIdx.x;
    f2[j]       = h1[(size_t)b * HAZ1 + j];
    f2[256 + j] = h1[(size_t)b * HAZ1 + 256 + j];
    __syncthreads();
    float a = bh2[j];
    for (int k = 0; k < HAZ1; k++) a += f2[k] * Wh2[(size_t)k * HAZ2 + j];
    h2[(size_t)b * HAZ2 + j] = fmaxf(a, 0.f);
}

__global__ __launch_bounds__(256) void k_out(
        const float* __restrict__ h2, const float* __restrict__ Wh3,
        float* __restrict__ out) {
    __shared__ float red[256];
    int b = blockIdx.x, t = threadIdx.x;
    red[t] = h2[(size_t)b * HAZ2 + t] * Wh3[t];
    __syncthreads();
    for (int o = 128; o > 0; o >>= 1) {
        if (t < o) red[t] += red[t + o];
        __syncthreads();
    }
    if (t == 0) out[b] = red[0];
}

// ---------------- launch ----------------
extern "C" void kernel_launch(void* const* d_in, const int* in_sizes, int n_in,
                              void* d_out, int out_size, void* d_ws, size_t ws_size,
                              hipStream_t stream) {
    const float* inp = (const float*)d_in[0];
    const int*   src = (const int*)d_in[1];
    const int*   dst = (const int*)d_in[2];
    const float* W0  = (const float*)d_in[3];
    const float* b0  = (const float*)d_in[4];
    const float* W1  = (const float*)d_in[5];
    const float* b1  = (const float*)d_in[6];
    const float* W2  = (const float*)d_in[7];
    const float* b2  = (const float*)d_in[8];
    const float* We  = (const float*)d_in[9];
    const float* Wh1 = (const float*)d_in[10];
    const float* bh1 = (const float*)d_in[11];
    const float* Wh2 = (const float*)d_in[12];
    const float* bh2 = (const float*)d_in[13];
    const float* Wh3 = (const float*)d_in[14];
    float* out = (float*)d_out;

    char* ws = (char*)d_ws;
    int*   dego = (int*)(ws + OFF_DEGO);
    int*   degi = (int*)(ws + OFF_DEGI);
    int*   cur  = (int*)(ws + OFF_CUR);
    float* wout = (float*)(ws + OFF_WOUT);
    float* win  = (float*)(ws + OFF_WIN);
    int*   ioff = (int*)(ws + OFF_IOFF);
    int*   csrc = (int*)(ws + OFF_CSRC);
    float* csrw = (float*)(ws + OFF_CSRW);
    float* hg   = (float*)(ws + OFF_HG);
    float* emb  = (float*)(ws + OFF_EMB);
    float* h1   = (float*)(ws + OFF_H1);
    float* h2   = (float*)(ws + OFF_H2);
    float* psum = (float*)(ws + OFF_PSUM);
    float* pmax = (float*)(ws + OFF_PMAX);
    float* avec = (float*)(ws + OFF_A);
    u16*   wt1h = (u16*)(ws + OFF_WT1H);
    u16*   wt2h = (u16*)(ws + OFF_WT2H);

    // ---- choose batch-chunk size CB ----
    // need = OFF_XBUF + CB * 2 * (NN*C_*2)  (two bf16 x buffers)
    // CB multiple of 16 (CBH%8==0 for the agg swizzle; CB*NN%GM==0).
    const size_t perb = (size_t)NN * C_ * 4;
    int CB = 128;
    while (CB > 16 && OFF_XBUF + (size_t)CB * perb > ws_size) CB >>= 1;
    int nchunk = B_ / CB;
    int CBH = CB / 2;
    int QBH = CBH / 8;

    u16* xB   = (u16*)(ws + OFF_XBUF);                              // agg out (GEMM A)
    u16* xAbf = (u16*)(ws + OFF_XBUF + (size_t)CB * NN * C_ * 2);   // bf16 x1

    // zeros: deg counters (6000 ints), hg, psum+pmax (contiguous 65536 floats)
    k_zero<<<dim3((6000 + 255) / 256), 256, 0, stream>>>((float*)dego, 6000);
    k_zero<<<dim3((65536 + 255) / 256), 256, 0, stream>>>(hg, 65536);
    k_zero<<<dim3((65536 + 255) / 256), 256, 0, stream>>>(psum, 65536);

    // graph normalization + CSR build + weight transpose
    k_deg<<<dim3((E_ + 255) / 256), 256, 0, stream>>>(src, dst, dego, degi);
    k_norm<<<dim3((NN + 255) / 256), 256, 0, stream>>>(dego, degi, wout, win);
    k_scan<<<1, 512, 0, stream>>>(degi, ioff);
    k_fill<<<dim3((E_ + 255) / 256), 256, 0, stream>>>(src, dst, wout, win, ioff, cur, csrc, csrw);
    k_prepw<<<256, 256, 0, stream>>>(W1, wt1h);
    k_prepw<<<256, 256, 0, stream>>>(W2, wt2h);

    // scalar conv of input feature (all B), layer-0 pooling from it
    k_agg_scalar<<<dim3((NN + 63) / 64, B_), 64, 0, stream>>>(inp, ioff, csrc, csrw, avec);
    k_pool0<<<B_, 256, 0, stream>>>(avec, W0, b0, hg);

    dim3 gridNB(NN, CBH);
    dim3 gridGemm(C_ / GN, (CB * NN) / GM);

    for (int c = 0; c < nchunk; ++c) {
        int b0g = c * CB;

        // layer 1: fused expand+agg -> xB (bf16); MFMA gemm + fused pool -> xA (bf16)
        k_agg_l1<<<gridNB, 64, 0, stream>>>(avec, ioff, csrc, csrw, W0, b0, xB, b0g);
        k_gemm_mfma<1><<<gridGemm, 256, 0, stream>>>(xB, wt1h, b1, xAbf, psum, pmax);
        k_pool_combine<<<CB, 256, 0, stream>>>(psum, pmax, hg, b0g);

        // layer 2: bf16 gather agg -> xB; MFMA gemm, pool only (no C write)
        k_agg_bf<<<gridNB, 64, 0, stream>>>(xAbf, ioff, csrc, csrw, xB, QBH);
        k_gemm_mfma<0><<<gridGemm, 256, 0, stream>>>(xB, wt2h, b2, nullptr, psum, pmax);
        k_pool_combine<<<CB, 256, 0, stream>>>(psum, pmax, hg, b0g);
    }

    // head
    k_embed<<<B_, 128, 0, stream>>>(inp, We, emb);
    k_mlp1<<<B_, 512, 0, stream>>>(emb, hg, Wh1, bh1, h1);
    k_mlp2<<<B_, 256, 0, stream>>>(h1, Wh2, bh2, h2);
    k_out<<<B_, 256, 0, stream>>>(h2, Wh3, out);
}